// Round 11
// baseline (4338.390 us; speedup 1.0000x reference)
//
#include <hip/hip_runtime.h>

#define B_     256
#define L_     128
#define D_     6
#define F_     200
#define FA_    39
#define FB_    10
#define FAB_   49        // FA + FB
#define PAD_   127       // L-1 padding atom index
#define LMASK  127       // L-1 (pow2): exact clamp for idx in [0,L)
#define NT     256
#define KC     (F_/4)    // 50 float4 chunks per F-row

__device__ __forceinline__ float lrelu(float x) { return x >= 0.0f ? x : 0.01f * x; }
__device__ __forceinline__ float sigm(float x)  { return 1.0f / (1.0f + __expf(-x)); }
__device__ __forceinline__ float dot4(float4 a, float4 b) {
    return a.x*b.x + a.y*b.y + a.z*b.z + a.w*b.w;
}

// ============================ ROUND 0 (NTILE=4) =============================
// LDS ~35.6 KB -> 4 blocks/CU. Computes atom/nbr embeddings + attn + GRU.
#define NT0 4
__global__ __launch_bounds__(NT, 4)
void fp_round0_kernel(
    const float* __restrict__ atom_list,   // [B,L,FA]
    const float* __restrict__ bond_list,   // [B,L,FB]
    const int*   __restrict__ atom_degree, // [B,L,D]
    const int*   __restrict__ bond_degree, // [B,L,D]
    const float* __restrict__ atom_W,      // [F,FA]
    const float* __restrict__ atom_b,      // [F]
    const float* __restrict__ nbr_W,       // [F,FAB]
    const float* __restrict__ nbr_b,       // [F]
    const float* __restrict__ align_W,     // [2F] (round 0)
    const float* __restrict__ align_b,     // [1]
    const float* __restrict__ attend_W,    // [F,F]
    const float* __restrict__ attend_b,    // [F]
    const float* __restrict__ gru_Wih,     // [3F,F]
    const float* __restrict__ gru_Whh,     // [3F,F]
    const float* __restrict__ gru_bih,     // [3F]
    const float* __restrict__ gru_bhh,     // [3F]
    float*       __restrict__ cur_out)     // [B,L,F] fp32 ws
{
    const int node0 = blockIdx.x * NT0;
    const int b     = node0 >> 7;
    const int tid   = threadIdx.x;

    __shared__ __align__(16) float cur_s  [NT0][F_];
    __shared__ __align__(16) float nbr_s  [NT0 * D_][F_];
    __shared__ __align__(16) float mixed_s[NT0][F_];
    __shared__ __align__(16) float ctx_s  [NT0][F_];
    __shared__ float alW_s[2 * F_];
    __shared__ float sc_s [NT0 * D_];
    __shared__ float asum_s[NT0];
    __shared__ int   nidx_s[NT0 * D_];
    __shared__ int   bidx_s[NT0 * D_];
    __shared__ __align__(16) float ga_s[NT0 * D_][FAB_ + 3];

    if (tid < NT0 * D_) {
        const int n = tid / D_, j = tid - n * D_;
        nidx_s[tid] = atom_degree[(node0 + n) * D_ + j] & LMASK;
        bidx_s[tid] = bond_degree[(node0 + n) * D_ + j] & LMASK;
    }
    for (int i = tid; i < 2 * F_; i += NT) alW_s[i] = align_W[i];

    // Phase A: atom embeddings for 4 nodes
    for (int idx = tid; idx < NT0 * F_; idx += NT) {
        const int n = idx / F_, f = idx - n * F_;
        const float* arow = atom_list + (size_t)(node0 + n) * FA_;
        const float* wrow = atom_W + (size_t)f * FA_;
        float acc = atom_b[f];
        #pragma unroll
        for (int k = 0; k < FA_; ++k) acc += arow[k] * wrow[k];
        cur_s[n][f] = lrelu(acc);
    }
    __syncthreads();

    // Phase B: gather + nbr embeddings
    for (int idx = tid; idx < NT0 * D_ * FAB_; idx += NT) {
        const int q = idx / FAB_, k = idx - q * FAB_;
        ga_s[q][k] = (k < FA_)
            ? atom_list[(size_t)(b * L_ + nidx_s[q]) * FA_ + k]
            : bond_list[(size_t)(b * L_ + bidx_s[q]) * FB_ + (k - FA_)];
    }
    __syncthreads();
    for (int idx = tid; idx < NT0 * D_ * F_; idx += NT) {
        const int q = idx / F_, f = idx - q * F_;
        const float* g    = ga_s[q];
        const float* wrow = nbr_W + (size_t)f * FAB_;
        float acc = nbr_b[f];
        #pragma unroll
        for (int k = 0; k < FAB_; ++k) acc += g[k] * wrow[k];
        nbr_s[q][f] = lrelu(acc);
    }
    __syncthreads();

    // Phase C: align scores (quad of lanes per (n,j); k = sub + 4*i)
    if (tid < NT0 * D_ * 4) {
        const int quad = tid >> 2, sub = tid & 3;
        const int n = quad / D_;
        float s = 0.0f;
        for (int i = 0; i < 50; ++i) {
            const int k = sub + 4 * i;
            s += cur_s[n][k] * alW_s[k];
        }
        for (int i = 0; i < 50; ++i) {
            const int k = sub + 4 * i;
            s += nbr_s[quad][k] * alW_s[F_ + k];
        }
        s += __shfl_xor(s, 1, 4);
        s += __shfl_xor(s, 2, 4);
        if (sub == 0) {
            float sc = lrelu(s + align_b[0]);
            if (nidx_s[quad] == PAD_) sc += -9.0e8f;
            sc_s[quad] = sc;
        }
    }
    __syncthreads();

    // masked softmax over D per node
    if (tid < NT0) {
        float m = sc_s[tid * D_];
        #pragma unroll
        for (int j = 1; j < D_; ++j) m = fmaxf(m, sc_s[tid * D_ + j]);
        float ex[D_]; float ssum = 0.0f;
        #pragma unroll
        for (int j = 0; j < D_; ++j) { ex[j] = __expf(sc_s[tid * D_ + j] - m); ssum += ex[j]; }
        const float inv = 1.0f / ssum;
        float as = 0.0f;
        #pragma unroll
        for (int j = 0; j < D_; ++j) {
            const float a = (nidx_s[tid * D_ + j] == PAD_) ? 0.0f : ex[j] * inv;
            sc_s[tid * D_ + j] = a;
            as += a;
        }
        asum_s[tid] = as;
    }
    __syncthreads();

    // Phase D: mixed = sum_j attn_j * nbr_j
    for (int idx = tid; idx < NT0 * F_; idx += NT) {
        const int n = idx / F_, k = idx - n * F_;
        float m = 0.0f;
        #pragma unroll
        for (int j = 0; j < D_; ++j) m += sc_s[n * D_ + j] * nbr_s[n * D_ + j][k];
        mixed_s[n][k] = m;
    }
    __syncthreads();

    // Phase E: ctx = elu(attend_W @ mixed + asum*b)
    if (tid < F_) {
        float acc[NT0];
        #pragma unroll
        for (int n = 0; n < NT0; ++n) acc[n] = 0.0f;
        const float4* w4 = (const float4*)(attend_W + (size_t)tid * F_);
        for (int kk = 0; kk < KC; ++kk) {
            const float4 w = w4[kk];
            #pragma unroll
            for (int n = 0; n < NT0; ++n)
                acc[n] += dot4(w, ((const float4*)mixed_s[n])[kk]);
        }
        const float bb = attend_b[tid];
        #pragma unroll
        for (int n = 0; n < NT0; ++n) {
            const float c = acc[n] + asum_s[n] * bb;
            ctx_s[n][tid] = (c > 0.0f) ? c : (__expf(c) - 1.0f);
        }
    }
    __syncthreads();

    // Phase F: GRU
    if (tid < F_) {
        float air[NT0], aiz[NT0], ain[NT0], ahr[NT0], ahz[NT0], ahn[NT0];
        #pragma unroll
        for (int n = 0; n < NT0; ++n)
            air[n] = aiz[n] = ain[n] = ahr[n] = ahz[n] = ahn[n] = 0.0f;
        const float4* wir4 = (const float4*)(gru_Wih + (size_t)tid * F_);
        const float4* wiz4 = (const float4*)(gru_Wih + (size_t)(F_   + tid) * F_);
        const float4* win4 = (const float4*)(gru_Wih + (size_t)(2*F_ + tid) * F_);
        const float4* whr4 = (const float4*)(gru_Whh + (size_t)tid * F_);
        const float4* whz4 = (const float4*)(gru_Whh + (size_t)(F_   + tid) * F_);
        const float4* whn4 = (const float4*)(gru_Whh + (size_t)(2*F_ + tid) * F_);
        for (int kk = 0; kk < KC; ++kk) {
            const float4 wr = wir4[kk], wz = wiz4[kk], wn = win4[kk];
            const float4 vr = whr4[kk], vz = whz4[kk], vn = whn4[kk];
            #pragma unroll
            for (int n = 0; n < NT0; ++n) {
                const float4 c = ((const float4*)ctx_s[n])[kk];
                const float4 h = ((const float4*)cur_s[n])[kk];
                air[n] += dot4(wr, c); aiz[n] += dot4(wz, c); ain[n] += dot4(wn, c);
                ahr[n] += dot4(vr, h); ahz[n] += dot4(vz, h); ahn[n] += dot4(vn, h);
            }
        }
        const float bir = gru_bih[tid], biz = gru_bih[F_ + tid], bin = gru_bih[2*F_ + tid];
        const float bhr = gru_bhh[tid], bhz = gru_bhh[F_ + tid], bhn = gru_bhh[2*F_ + tid];
        #pragma unroll
        for (int n = 0; n < NT0; ++n) {
            const float r  = sigm(air[n] + bir + ahr[n] + bhr);
            const float z  = sigm(aiz[n] + biz + ahz[n] + bhz);
            const float nn = tanhf(ain[n] + bin + r * (ahn[n] + bhn));
            const float h  = (1.0f - z) * nn + z * cur_s[n][tid];
            cur_out[(size_t)(node0 + n) * F_ + tid] = fmaxf(h, 0.0f);
        }
    }
}

// ============================ ROUND 1 (NTILE=8) =============================
// No nbr_s/ga_s: neighbor features are rows of cur_in, read from L1/L2.
// LDS ~21 KB -> 4 blocks/CU (VGPR-capped via launch_bounds).
#define NT1 8
__global__ __launch_bounds__(NT, 4)
void fp_round1_kernel(
    const int*   __restrict__ atom_degree, // [B,L,D]
    const float* __restrict__ align_W,     // [2F] (round 1)
    const float* __restrict__ align_b,     // [1]
    const float* __restrict__ attend_W,    // [F,F]
    const float* __restrict__ attend_b,    // [F]
    const float* __restrict__ gru_Wih,     // [3F,F]
    const float* __restrict__ gru_Whh,     // [3F,F]
    const float* __restrict__ gru_bih,     // [3F]
    const float* __restrict__ gru_bhh,     // [3F]
    const float* __restrict__ cur_in,      // [B,L,F] fp32 ws
    float*       __restrict__ out)         // [B,L,F] fp32 d_out
{
    const int node0 = blockIdx.x * NT1;
    const int b     = node0 >> 7;
    const int tid   = threadIdx.x;

    __shared__ __align__(16) float cur_s  [NT1][F_];
    __shared__ __align__(16) float mixed_s[NT1][F_];
    __shared__ __align__(16) float ctx_s  [NT1][F_];
    __shared__ float alW_s[2 * F_];
    __shared__ float sc_s [NT1 * D_];
    __shared__ float asum_s[NT1];
    __shared__ int   nidx_s[NT1 * D_];

    if (tid < NT1 * D_) {
        const int n = tid / D_, j = tid - n * D_;
        nidx_s[tid] = atom_degree[(node0 + n) * D_ + j] & LMASK;
    }
    for (int i = tid; i < 2 * F_; i += NT) alW_s[i] = align_W[i];

    // Phase A: own cur rows (float4, coalesced)
    for (int idx = tid; idx < NT1 * KC; idx += NT) {
        const int n = idx / KC, kk = idx - n * KC;
        ((float4*)cur_s[n])[kk] =
            ((const float4*)(cur_in + (size_t)(node0 + n) * F_))[kk];
    }
    __syncthreads();

    // Phase C: align scores; nbr half read directly from global cur_in
    if (tid < NT1 * D_ * 4) {
        const int quad = tid >> 2, sub = tid & 3;
        const int n = quad / D_;
        const float* nrow = cur_in + (size_t)(b * L_ + nidx_s[quad]) * F_;
        float s = 0.0f;
        for (int i = 0; i < 50; ++i) {
            const int k = sub + 4 * i;
            s += cur_s[n][k] * alW_s[k];
        }
        for (int i = 0; i < 50; ++i) {
            const int k = sub + 4 * i;
            s += nrow[k] * alW_s[F_ + k];
        }
        s += __shfl_xor(s, 1, 4);
        s += __shfl_xor(s, 2, 4);
        if (sub == 0) {
            float sc = lrelu(s + align_b[0]);
            if (nidx_s[quad] == PAD_) sc += -9.0e8f;
            sc_s[quad] = sc;
        }
    }
    __syncthreads();

    // masked softmax
    if (tid < NT1) {
        float m = sc_s[tid * D_];
        #pragma unroll
        for (int j = 1; j < D_; ++j) m = fmaxf(m, sc_s[tid * D_ + j]);
        float ex[D_]; float ssum = 0.0f;
        #pragma unroll
        for (int j = 0; j < D_; ++j) { ex[j] = __expf(sc_s[tid * D_ + j] - m); ssum += ex[j]; }
        const float inv = 1.0f / ssum;
        float as = 0.0f;
        #pragma unroll
        for (int j = 0; j < D_; ++j) {
            const float a = (nidx_s[tid * D_ + j] == PAD_) ? 0.0f : ex[j] * inv;
            sc_s[tid * D_ + j] = a;
            as += a;
        }
        asum_s[tid] = as;
    }
    __syncthreads();

    // Phase D: mixed[n] = sum_j attn_j * cur_in[nbr_j]  (float4, coalesced)
    for (int idx = tid; idx < NT1 * KC; idx += NT) {
        const int n = idx / KC, kk = idx - n * KC;
        float4 m = make_float4(0.f, 0.f, 0.f, 0.f);
        #pragma unroll
        for (int j = 0; j < D_; ++j) {
            const float a = sc_s[n * D_ + j];
            const float4 v = ((const float4*)(cur_in +
                              (size_t)(b * L_ + nidx_s[n * D_ + j]) * F_))[kk];
            m.x += a * v.x; m.y += a * v.y; m.z += a * v.z; m.w += a * v.w;
        }
        ((float4*)mixed_s[n])[kk] = m;
    }
    __syncthreads();

    // Phase E
    if (tid < F_) {
        float acc[NT1];
        #pragma unroll
        for (int n = 0; n < NT1; ++n) acc[n] = 0.0f;
        const float4* w4 = (const float4*)(attend_W + (size_t)tid * F_);
        for (int kk = 0; kk < KC; ++kk) {
            const float4 w = w4[kk];
            #pragma unroll
            for (int n = 0; n < NT1; ++n)
                acc[n] += dot4(w, ((const float4*)mixed_s[n])[kk]);
        }
        const float bb = attend_b[tid];
        #pragma unroll
        for (int n = 0; n < NT1; ++n) {
            const float c = acc[n] + asum_s[n] * bb;
            ctx_s[n][tid] = (c > 0.0f) ? c : (__expf(c) - 1.0f);
        }
    }
    __syncthreads();

    // Phase F: GRU
    if (tid < F_) {
        float air[NT1], aiz[NT1], ain[NT1], ahr[NT1], ahz[NT1], ahn[NT1];
        #pragma unroll
        for (int n = 0; n < NT1; ++n)
            air[n] = aiz[n] = ain[n] = ahr[n] = ahz[n] = ahn[n] = 0.0f;
        const float4* wir4 = (const float4*)(gru_Wih + (size_t)tid * F_);
        const float4* wiz4 = (const float4*)(gru_Wih + (size_t)(F_   + tid) * F_);
        const float4* win4 = (const float4*)(gru_Wih + (size_t)(2*F_ + tid) * F_);
        const float4* whr4 = (const float4*)(gru_Whh + (size_t)tid * F_);
        const float4* whz4 = (const float4*)(gru_Whh + (size_t)(F_   + tid) * F_);
        const float4* whn4 = (const float4*)(gru_Whh + (size_t)(2*F_ + tid) * F_);
        for (int kk = 0; kk < KC; ++kk) {
            const float4 wr = wir4[kk], wz = wiz4[kk], wn = win4[kk];
            const float4 vr = whr4[kk], vz = whz4[kk], vn = whn4[kk];
            #pragma unroll
            for (int n = 0; n < NT1; ++n) {
                const float4 c = ((const float4*)ctx_s[n])[kk];
                const float4 h = ((const float4*)cur_s[n])[kk];
                air[n] += dot4(wr, c); aiz[n] += dot4(wz, c); ain[n] += dot4(wn, c);
                ahr[n] += dot4(vr, h); ahz[n] += dot4(vz, h); ahn[n] += dot4(vn, h);
            }
        }
        const float bir = gru_bih[tid], biz = gru_bih[F_ + tid], bin = gru_bih[2*F_ + tid];
        const float bhr = gru_bhh[tid], bhz = gru_bhh[F_ + tid], bhn = gru_bhh[2*F_ + tid];
        #pragma unroll
        for (int n = 0; n < NT1; ++n) {
            const float r  = sigm(air[n] + bir + ahr[n] + bhr);
            const float z  = sigm(aiz[n] + biz + ahz[n] + bhz);
            const float nn = tanhf(ain[n] + bin + r * (ahn[n] + bhn));
            const float h  = (1.0f - z) * nn + z * cur_s[n][tid];
            out[(size_t)(node0 + n) * F_ + tid] = fmaxf(h, 0.0f);
        }
    }
}

extern "C" __attribute__((visibility("default")))
void kernel_launch(void* const* d_in, const int* in_sizes, int n_in,
                   void* d_out, int out_size, void* d_ws, size_t ws_size,
                   hipStream_t stream) {
    const float* atom_list = (const float*)d_in[0];
    const float* bond_list = (const float*)d_in[1];
    const int*   atom_deg  = (const int*)d_in[2];
    const int*   bond_deg  = (const int*)d_in[3];
    const float* atom_W    = (const float*)d_in[4];
    const float* atom_b    = (const float*)d_in[5];
    const float* nbr_W     = (const float*)d_in[6];
    const float* nbr_b     = (const float*)d_in[7];
    const float* align_W   = (const float*)d_in[8];   // [R,1,2F]
    const float* align_b   = (const float*)d_in[9];   // [R,1]
    const float* attend_W  = (const float*)d_in[10];  // [R,F,F]
    const float* attend_b  = (const float*)d_in[11];  // [R,F]
    const float* gru_Wih   = (const float*)d_in[12];  // [R,3F,F]
    const float* gru_Whh   = (const float*)d_in[13];  // [R,3F,F]
    const float* gru_bih   = (const float*)d_in[14];  // [R,3F]
    const float* gru_bhh   = (const float*)d_in[15];  // [R,3F]

    float* cur_ws = (float*)d_ws;      // [B,L,F] fp32, 26.2 MB (ws = 256 MB)
    float* out    = (float*)d_out;     // [B,L,F] fp32

    fp_round0_kernel<<<dim3(B_ * L_ / NT0), dim3(NT), 0, stream>>>(
        atom_list, bond_list, atom_deg, bond_deg,
        atom_W, atom_b, nbr_W, nbr_b,
        align_W, align_b, attend_W, attend_b,
        gru_Wih, gru_Whh, gru_bih, gru_bhh,
        cur_ws);

    fp_round1_kernel<<<dim3(B_ * L_ / NT1), dim3(NT), 0, stream>>>(
        atom_deg,
        align_W + 2 * F_,
        align_b + 1,
        attend_W + (size_t)F_ * F_,
        attend_b + F_,
        gru_Wih + (size_t)3 * F_ * F_,
        gru_Whh + (size_t)3 * F_ * F_,
        gru_bih + 3 * F_,
        gru_bhh + 3 * F_,
        cur_ws, out);
}

// Round 12
// 2038.700 us; speedup vs baseline: 2.1280x; 2.1280x over previous
//
#include <hip/hip_runtime.h>

#define B_     256
#define L_     128
#define D_     6
#define F_     200
#define FA_    39
#define FB_    10
#define FAB_   49        // FA + FB
#define PAD_   127       // L-1 padding atom index
#define LMASK  127       // L-1 (pow2): exact clamp for idx in [0,L)
#define NT     256
#define KC     (F_/4)    // 50 float4 chunks per F-row
#define NTILE  16        // nodes per block (divides L)
#define NQ     (NTILE * D_)   // 96 (node,neighbor) pairs

__device__ __forceinline__ float lrelu(float x) { return x >= 0.0f ? x : 0.01f * x; }
__device__ __forceinline__ float sigm(float x)  { return 1.0f / (1.0f + __expf(-x)); }
__device__ __forceinline__ float dot4(float4 a, float4 b) {
    return a.x*b.x + a.y*b.y + a.z*b.z + a.w*b.w;
}

// Shared epilogue: Phase E (ctx) + two-pass GRU (Phase F).
// Requires cur_s/mixed_s/ctx_s[NTILE][F_], asum_s[NTILE] in LDS.
__device__ __forceinline__ void ctx_and_gru(
    const float* __restrict__ attend_W, const float* __restrict__ attend_b,
    const float* __restrict__ gru_Wih,  const float* __restrict__ gru_Whh,
    const float* __restrict__ gru_bih,  const float* __restrict__ gru_bhh,
    float (*cur_s)[F_], float (*mixed_s)[F_], float (*ctx_s)[F_],
    const float* asum_s, float* __restrict__ dst, int node0, int tid)
{
    // ---- Phase E: ctx[n][f] = elu( attend_W[f]·mixed[n] + asum[n]*b[f] ) ----
    if (tid < F_) {
        float acc[NTILE];
        #pragma unroll
        for (int n = 0; n < NTILE; ++n) acc[n] = 0.0f;
        const float4* w4 = (const float4*)(attend_W + (size_t)tid * F_);
        for (int kk = 0; kk < KC; ++kk) {
            const float4 w = w4[kk];
            #pragma unroll
            for (int n = 0; n < NTILE; ++n)
                acc[n] += dot4(w, ((const float4*)mixed_s[n])[kk]);
        }
        const float bb = attend_b[tid];
        #pragma unroll
        for (int n = 0; n < NTILE; ++n) {
            const float c = acc[n] + asum_s[n] * bb;
            ctx_s[n][tid] = (c > 0.0f) ? c : (__expf(c) - 1.0f);
        }
    }
    __syncthreads();

    // ---- Phase F: GRU, two passes to bound VGPR ----
    if (tid < F_) {
        const float4* wr4 = (const float4*)(gru_Wih + (size_t)tid * F_);
        const float4* wz4 = (const float4*)(gru_Wih + (size_t)(F_   + tid) * F_);
        const float4* wn4 = (const float4*)(gru_Wih + (size_t)(2*F_ + tid) * F_);
        const float4* vr4 = (const float4*)(gru_Whh + (size_t)tid * F_);
        const float4* vz4 = (const float4*)(gru_Whh + (size_t)(F_   + tid) * F_);
        const float4* vn4 = (const float4*)(gru_Whh + (size_t)(2*F_ + tid) * F_);

        float r_[NTILE], z_[NTILE];
        {   // pass 1: r and z gates (4 weight streams, 64 accs)
            float air[NTILE], aiz[NTILE], ahr[NTILE], ahz[NTILE];
            #pragma unroll
            for (int n = 0; n < NTILE; ++n) air[n] = aiz[n] = ahr[n] = ahz[n] = 0.0f;
            for (int kk = 0; kk < KC; ++kk) {
                const float4 wr = wr4[kk], wz = wz4[kk];
                const float4 vr = vr4[kk], vz = vz4[kk];
                #pragma unroll
                for (int n = 0; n < NTILE; ++n) {
                    const float4 c = ((const float4*)ctx_s[n])[kk];
                    const float4 h = ((const float4*)cur_s[n])[kk];
                    air[n] += dot4(wr, c); aiz[n] += dot4(wz, c);
                    ahr[n] += dot4(vr, h); ahz[n] += dot4(vz, h);
                }
            }
            const float bir = gru_bih[tid], biz = gru_bih[F_ + tid];
            const float bhr = gru_bhh[tid], bhz = gru_bhh[F_ + tid];
            #pragma unroll
            for (int n = 0; n < NTILE; ++n) {
                r_[n] = sigm(air[n] + bir + ahr[n] + bhr);
                z_[n] = sigm(aiz[n] + biz + ahz[n] + bhz);
            }
        }
        {   // pass 2: n gate (2 weight streams, 32 accs) + combine + store
            float ain[NTILE], ahn[NTILE];
            #pragma unroll
            for (int n = 0; n < NTILE; ++n) ain[n] = ahn[n] = 0.0f;
            for (int kk = 0; kk < KC; ++kk) {
                const float4 wn = wn4[kk], vn = vn4[kk];
                #pragma unroll
                for (int n = 0; n < NTILE; ++n) {
                    ain[n] += dot4(wn, ((const float4*)ctx_s[n])[kk]);
                    ahn[n] += dot4(vn, ((const float4*)cur_s[n])[kk]);
                }
            }
            const float bin = gru_bih[2*F_ + tid], bhn = gru_bhh[2*F_ + tid];
            #pragma unroll
            for (int n = 0; n < NTILE; ++n) {
                const float nn = tanhf(ain[n] + bin + r_[n] * (ahn[n] + bhn));
                const float h  = (1.0f - z_[n]) * nn + z_[n] * cur_s[n][tid];
                dst[(size_t)(node0 + n) * F_ + tid] = fmaxf(h, 0.0f);
            }
        }
    }
}

// ============================ ROUND 0 =============================
// nbr embeddings are RECOMPUTED in score & mix phases (nbr_W is L1-resident)
// so no nbr_s array: LDS ~60 KB -> 2 blocks/CU at NTILE=16.
__global__ __launch_bounds__(NT)
void fp_round0_kernel(
    const float* __restrict__ atom_list,   // [B,L,FA]
    const float* __restrict__ bond_list,   // [B,L,FB]
    const int*   __restrict__ atom_degree, // [B,L,D]
    const int*   __restrict__ bond_degree, // [B,L,D]
    const float* __restrict__ atom_W,      // [F,FA]
    const float* __restrict__ atom_b,      // [F]
    const float* __restrict__ nbr_W,       // [F,FAB]
    const float* __restrict__ nbr_b,       // [F]
    const float* __restrict__ align_W,     // [2F] (round 0)
    const float* __restrict__ align_b,     // [1]
    const float* __restrict__ attend_W,    // [F,F]
    const float* __restrict__ attend_b,    // [F]
    const float* __restrict__ gru_Wih,     // [3F,F]
    const float* __restrict__ gru_Whh,     // [3F,F]
    const float* __restrict__ gru_bih,     // [3F]
    const float* __restrict__ gru_bhh,     // [3F]
    float*       __restrict__ cur_out)     // [B,L,F] fp32 ws
{
    const int node0 = blockIdx.x * NTILE;
    const int b     = node0 >> 7;
    const int tid   = threadIdx.x;

    __shared__ __align__(16) float cur_s  [NTILE][F_];   // 12.8K
    __shared__ __align__(16) float mixed_s[NTILE][F_];   // 12.8K
    __shared__ __align__(16) float ctx_s  [NTILE][F_];   // 12.8K
    __shared__ float ga_s[NQ][FAB_ + 3];                 // 20K gathered raw rows
    __shared__ float alW_s[2 * F_];                      // 1.6K
    __shared__ float sc_s [NQ];
    __shared__ float asum_s[NTILE];
    __shared__ int   nidx_s[NQ];
    __shared__ int   bidx_s[NQ];

    if (tid < NQ) {
        const int n = tid / D_, j = tid - n * D_;
        nidx_s[tid] = atom_degree[(node0 + n) * D_ + j] & LMASK;
        bidx_s[tid] = bond_degree[(node0 + n) * D_ + j] & LMASK;
    }
    for (int i = tid; i < 2 * F_; i += NT) alW_s[i] = align_W[i];
    __syncthreads();

    // Phase A: atom embeddings; Phase GA: gather raw neighbor rows
    for (int idx = tid; idx < NQ * FAB_; idx += NT) {
        const int q = idx / FAB_, k = idx - q * FAB_;
        ga_s[q][k] = (k < FA_)
            ? atom_list[(size_t)(b * L_ + nidx_s[q]) * FA_ + k]
            : bond_list[(size_t)(b * L_ + bidx_s[q]) * FB_ + (k - FA_)];
    }
    for (int idx = tid; idx < NTILE * F_; idx += NT) {
        const int n = idx / F_, f = idx - n * F_;
        const float* arow = atom_list + (size_t)(node0 + n) * FA_;
        const float* wrow = atom_W + (size_t)f * FA_;
        float acc = atom_b[f];
        #pragma unroll
        for (int k = 0; k < FA_; ++k) acc += arow[k] * wrow[k];
        cur_s[n][f] = lrelu(acc);
    }
    __syncthreads();

    // Phase C: align scores; nbr embedding recomputed on the fly.
    // 2 lanes per (n,j) pair, f parity split.
    if (tid < NQ * 2) {
        const int q = tid >> 1, sub = tid & 1;
        const int n = q / D_;
        float s = 0.0f;
        for (int k = sub; k < F_; k += 2) s += cur_s[n][k] * alW_s[k];
        const float* g = ga_s[q];
        for (int f = sub; f < F_; f += 2) {
            const float* wrow = nbr_W + (size_t)f * FAB_;
            float v = nbr_b[f];
            #pragma unroll
            for (int k = 0; k < FAB_; ++k) v += g[k] * wrow[k];
            s += lrelu(v) * alW_s[F_ + f];
        }
        s += __shfl_xor(s, 1, 2);
        if (sub == 0) {
            float sc = lrelu(s + align_b[0]);
            if (nidx_s[q] == PAD_) sc += -9.0e8f;
            sc_s[q] = sc;
        }
    }
    __syncthreads();

    // masked softmax over D per node
    if (tid < NTILE) {
        float m = sc_s[tid * D_];
        #pragma unroll
        for (int j = 1; j < D_; ++j) m = fmaxf(m, sc_s[tid * D_ + j]);
        float ex[D_]; float ssum = 0.0f;
        #pragma unroll
        for (int j = 0; j < D_; ++j) { ex[j] = __expf(sc_s[tid * D_ + j] - m); ssum += ex[j]; }
        const float inv = 1.0f / ssum;
        float as = 0.0f;
        #pragma unroll
        for (int j = 0; j < D_; ++j) {
            const float a = (nidx_s[tid * D_ + j] == PAD_) ? 0.0f : ex[j] * inv;
            sc_s[tid * D_ + j] = a;
            as += a;
        }
        asum_s[tid] = as;
    }
    __syncthreads();

    // Phase D: mixed[n][f] = sum_j attn * lrelu(nbr_W[f]·ga[n,j] + nbr_b[f])
    for (int idx = tid; idx < NTILE * F_; idx += NT) {
        const int n = idx / F_, f = idx - n * F_;
        const float* wrow = nbr_W + (size_t)f * FAB_;
        const float bb = nbr_b[f];
        float m = 0.0f;
        #pragma unroll
        for (int j = 0; j < D_; ++j) {
            const float* g = ga_s[n * D_ + j];
            float v = bb;
            #pragma unroll
            for (int k = 0; k < FAB_; ++k) v += g[k] * wrow[k];
            m += sc_s[n * D_ + j] * lrelu(v);
        }
        mixed_s[n][f] = m;
    }
    __syncthreads();

    ctx_and_gru(attend_W, attend_b, gru_Wih, gru_Whh, gru_bih, gru_bhh,
                cur_s, mixed_s, ctx_s, asum_s, cur_out, node0, tid);
}

// ============================ ROUND 1 =============================
// Neighbor features are rows of cur_in (global, L2-hot). LDS ~41 KB.
__global__ __launch_bounds__(NT)
void fp_round1_kernel(
    const int*   __restrict__ atom_degree, // [B,L,D]
    const float* __restrict__ align_W,     // [2F] (round 1)
    const float* __restrict__ align_b,     // [1]
    const float* __restrict__ attend_W,    // [F,F]
    const float* __restrict__ attend_b,    // [F]
    const float* __restrict__ gru_Wih,     // [3F,F]
    const float* __restrict__ gru_Whh,     // [3F,F]
    const float* __restrict__ gru_bih,     // [3F]
    const float* __restrict__ gru_bhh,     // [3F]
    const float* __restrict__ cur_in,      // [B,L,F] fp32 ws
    float*       __restrict__ out)         // [B,L,F] fp32 d_out
{
    const int node0 = blockIdx.x * NTILE;
    const int b     = node0 >> 7;
    const int tid   = threadIdx.x;

    __shared__ __align__(16) float cur_s  [NTILE][F_];
    __shared__ __align__(16) float mixed_s[NTILE][F_];
    __shared__ __align__(16) float ctx_s  [NTILE][F_];
    __shared__ float alW_s[2 * F_];
    __shared__ float sc_s [NQ];
    __shared__ float asum_s[NTILE];
    __shared__ int   nidx_s[NQ];

    if (tid < NQ) {
        const int n = tid / D_, j = tid - n * D_;
        nidx_s[tid] = atom_degree[(node0 + n) * D_ + j] & LMASK;
    }
    for (int i = tid; i < 2 * F_; i += NT) alW_s[i] = align_W[i];
    __syncthreads();

    // Phase A: own cur rows (float4, coalesced)
    for (int idx = tid; idx < NTILE * KC; idx += NT) {
        const int n = idx / KC, kk = idx - n * KC;
        ((float4*)cur_s[n])[kk] =
            ((const float4*)(cur_in + (size_t)(node0 + n) * F_))[kk];
    }
    __syncthreads();

    // Phase C: scores; 2 lanes per pair, neighbor row read from global
    if (tid < NQ * 2) {
        const int q = tid >> 1, sub = tid & 1;
        const int n = q / D_;
        const float* nrow = cur_in + (size_t)(b * L_ + nidx_s[q]) * F_;
        float s = 0.0f;
        for (int k = sub; k < F_; k += 2)
            s += cur_s[n][k] * alW_s[k] + nrow[k] * alW_s[F_ + k];
        s += __shfl_xor(s, 1, 2);
        if (sub == 0) {
            float sc = lrelu(s + align_b[0]);
            if (nidx_s[q] == PAD_) sc += -9.0e8f;
            sc_s[q] = sc;
        }
    }
    __syncthreads();

    // masked softmax
    if (tid < NTILE) {
        float m = sc_s[tid * D_];
        #pragma unroll
        for (int j = 1; j < D_; ++j) m = fmaxf(m, sc_s[tid * D_ + j]);
        float ex[D_]; float ssum = 0.0f;
        #pragma unroll
        for (int j = 0; j < D_; ++j) { ex[j] = __expf(sc_s[tid * D_ + j] - m); ssum += ex[j]; }
        const float inv = 1.0f / ssum;
        float as = 0.0f;
        #pragma unroll
        for (int j = 0; j < D_; ++j) {
            const float a = (nidx_s[tid * D_ + j] == PAD_) ? 0.0f : ex[j] * inv;
            sc_s[tid * D_ + j] = a;
            as += a;
        }
        asum_s[tid] = as;
    }
    __syncthreads();

    // Phase D: mixed[n] = sum_j attn_j * cur_in[nbr_j] (float4 gathers)
    for (int idx = tid; idx < NTILE * KC; idx += NT) {
        const int n = idx / KC, kk = idx - n * KC;
        float4 m = make_float4(0.f, 0.f, 0.f, 0.f);
        #pragma unroll
        for (int j = 0; j < D_; ++j) {
            const float a = sc_s[n * D_ + j];
            const float4 v = ((const float4*)(cur_in +
                              (size_t)(b * L_ + nidx_s[n * D_ + j]) * F_))[kk];
            m.x += a * v.x; m.y += a * v.y; m.z += a * v.z; m.w += a * v.w;
        }
        ((float4*)mixed_s[n])[kk] = m;
    }
    __syncthreads();

    ctx_and_gru(attend_W, attend_b, gru_Wih, gru_Whh, gru_bih, gru_bhh,
                cur_s, mixed_s, ctx_s, asum_s, out, node0, tid);
}

extern "C" __attribute__((visibility("default")))
void kernel_launch(void* const* d_in, const int* in_sizes, int n_in,
                   void* d_out, int out_size, void* d_ws, size_t ws_size,
                   hipStream_t stream) {
    const float* atom_list = (const float*)d_in[0];
    const float* bond_list = (const float*)d_in[1];
    const int*   atom_deg  = (const int*)d_in[2];
    const int*   bond_deg  = (const int*)d_in[3];
    const float* atom_W    = (const float*)d_in[4];
    const float* atom_b    = (const float*)d_in[5];
    const float* nbr_W     = (const float*)d_in[6];
    const float* nbr_b     = (const float*)d_in[7];
    const float* align_W   = (const float*)d_in[8];   // [R,1,2F]
    const float* align_b   = (const float*)d_in[9];   // [R,1]
    const float* attend_W  = (const float*)d_in[10];  // [R,F,F]
    const float* attend_b  = (const float*)d_in[11];  // [R,F]
    const float* gru_Wih   = (const float*)d_in[12];  // [R,3F,F]
    const float* gru_Whh   = (const float*)d_in[13];  // [R,3F,F]
    const float* gru_bih   = (const float*)d_in[14];  // [R,3F]
    const float* gru_bhh   = (const float*)d_in[15];  // [R,3F]

    float* cur_ws = (float*)d_ws;      // [B,L,F] fp32, 26.2 MB (ws = 256 MB)
    float* out    = (float*)d_out;     // [B,L,F] fp32

    const dim3 grid(B_ * L_ / NTILE);  // 2048
    const dim3 block(NT);

    fp_round0_kernel<<<grid, block, 0, stream>>>(
        atom_list, bond_list, atom_deg, bond_deg,
        atom_W, atom_b, nbr_W, nbr_b,
        align_W, align_b, attend_W, attend_b,
        gru_Wih, gru_Whh, gru_bih, gru_bhh,
        cur_ws);

    fp_round1_kernel<<<grid, block, 0, stream>>>(
        atom_deg,
        align_W + 2 * F_,
        align_b + 1,
        attend_W + (size_t)F_ * F_,
        attend_b + F_,
        gru_Wih + (size_t)3 * F_ * F_,
        gru_Whh + (size_t)3 * F_ * F_,
        gru_bih + 3 * F_,
        gru_bhh + 3 * F_,
        cur_ws, out);
}

// Round 13
// 1595.581 us; speedup vs baseline: 2.7190x; 1.2777x over previous
//
#include <hip/hip_runtime.h>

#define B_     256
#define L_     128
#define D_     6
#define F_     200
#define FA_    39
#define FB_    10
#define FAB_   49
#define PAD_   127       // L-1 padding atom index
#define LMASK  127
#define NT     256
#define KC     (F_/4)    // 50 float4 chunks per F-row
#define NTILE  16
#define NQ     (NTILE * D_)   // 96 pairs
#define NF     (B_ * L_ * F_) // 6,553,600 floats
#define MSZ    (F_ * F_)      // 40,000 floats per matrix

__device__ __forceinline__ float lrelu(float x) { return x >= 0.0f ? x : 0.01f * x; }
__device__ __forceinline__ float sigm(float x)  { return 1.0f / (1.0f + __expf(-x)); }
__device__ __forceinline__ float dot4(float4 a, float4 b) {
    return a.x*b.x + a.y*b.y + a.z*b.z + a.w*b.w;
}
// coalesced blocked-transposed weight load: lane tid gets W[tid][4kk..4kk+3]
#define WLOAD(base, kk) (((const float4*)((base) + (size_t)(kk) * (F_ * 4)))[tid])

// ============== prep: cur0 = lrelu(atom emb), PA/PB partial nbr emb ==============
#define PN 8
__global__ __launch_bounds__(NT)
void prep_kernel(const float* __restrict__ atom_list, const float* __restrict__ bond_list,
                 const float* __restrict__ atom_W, const float* __restrict__ atom_b,
                 const float* __restrict__ nbr_W,
                 float* __restrict__ cur0, float* __restrict__ PA, float* __restrict__ PB)
{
    const int node0 = blockIdx.x * PN;
    const int tid   = threadIdx.x;
    __shared__ float ga[PN][FA_ + 1];
    __shared__ float gb[PN][FB_ + 2];
    for (int idx = tid; idx < PN * FA_; idx += NT) {
        const int n = idx / FA_, k = idx - n * FA_;
        ga[n][k] = atom_list[(size_t)(node0 + n) * FA_ + k];
    }
    for (int idx = tid; idx < PN * FB_; idx += NT) {
        const int n = idx / FB_, k = idx - n * FB_;
        gb[n][k] = bond_list[(size_t)(node0 + n) * FB_ + k];
    }
    __syncthreads();
    for (int idx = tid; idx < PN * F_; idx += NT) {
        const int n = idx / F_, f = idx - n * F_;
        const float* wa = atom_W + (size_t)f * FA_;
        const float* wn = nbr_W + (size_t)f * FAB_;
        float accA = atom_b[f], accPA = 0.0f, accPB = 0.0f;
        #pragma unroll
        for (int k = 0; k < FA_; ++k) { accA += ga[n][k] * wa[k]; accPA += ga[n][k] * wn[k]; }
        #pragma unroll
        for (int k = 0; k < FB_; ++k) accPB += gb[n][k] * wn[FA_ + k];
        const size_t o = (size_t)(node0 + n) * F_ + f;
        cur0[o] = lrelu(accA);
        PA[o]   = accPA;
        PB[o]   = accPB;
    }
}

// ===== transpose 14 F×F matrices into blocked layout WT4[kk][f][j] =====
__global__ void transpose_kernel(const float* __restrict__ attend_W,
                                 const float* __restrict__ gru_Wih,
                                 const float* __restrict__ gru_Whh,
                                 float* __restrict__ WT)
{
    const int i = blockIdx.x * blockDim.x + threadIdx.x;
    if (i >= 14 * MSZ) return;
    const int m = i / MSZ, rem = i - m * MSZ;
    const int f = rem / F_, k = rem - f * F_;
    const int r = m / 7, t = m - r * 7;
    const float* src;
    if (t == 0)      src = attend_W + (size_t)r * MSZ;
    else if (t <= 3) src = gru_Wih + (size_t)r * 3 * MSZ + (size_t)(t - 1) * MSZ;
    else             src = gru_Whh + (size_t)r * 3 * MSZ + (size_t)(t - 4) * MSZ;
    WT[(size_t)m * MSZ + (size_t)(k >> 2) * (F_ * 4) + f * 4 + (k & 3)] =
        src[(size_t)f * F_ + k];
}

// ============ shared epilogue: Phase E (ctx) + two-pass GRU ============
__device__ __forceinline__ void ctx_and_gru(
    const float* __restrict__ WT,        // 7 blocked matrices this round
    const float* __restrict__ attend_b,
    const float* __restrict__ gru_bih,  const float* __restrict__ gru_bhh,
    float (*cur_s)[F_], float (*mixed_s)[F_], float (*ctx_s)[F_],
    const float* asum_s, float* __restrict__ dst, int node0, int tid)
{
    const float* aT  = WT;
    const float* wrT = WT + 1 * MSZ;
    const float* wzT = WT + 2 * MSZ;
    const float* wnT = WT + 3 * MSZ;
    const float* vrT = WT + 4 * MSZ;
    const float* vzT = WT + 5 * MSZ;
    const float* vnT = WT + 6 * MSZ;

    if (tid < F_) {
        float acc[NTILE];
        #pragma unroll
        for (int n = 0; n < NTILE; ++n) acc[n] = 0.0f;
        for (int kk = 0; kk < KC; ++kk) {
            const float4 w = WLOAD(aT, kk);
            #pragma unroll
            for (int n = 0; n < NTILE; ++n)
                acc[n] += dot4(w, ((const float4*)mixed_s[n])[kk]);
        }
        const float bb = attend_b[tid];
        #pragma unroll
        for (int n = 0; n < NTILE; ++n) {
            const float c = acc[n] + asum_s[n] * bb;
            ctx_s[n][tid] = (c > 0.0f) ? c : (__expf(c) - 1.0f);
        }
    }
    __syncthreads();

    if (tid < F_) {
        float r_[NTILE], z_[NTILE];
        {   // pass 1: r, z gates
            float air[NTILE], aiz[NTILE], ahr[NTILE], ahz[NTILE];
            #pragma unroll
            for (int n = 0; n < NTILE; ++n) air[n] = aiz[n] = ahr[n] = ahz[n] = 0.0f;
            for (int kk = 0; kk < KC; ++kk) {
                const float4 wr = WLOAD(wrT, kk), wz = WLOAD(wzT, kk);
                const float4 vr = WLOAD(vrT, kk), vz = WLOAD(vzT, kk);
                #pragma unroll
                for (int n = 0; n < NTILE; ++n) {
                    const float4 c = ((const float4*)ctx_s[n])[kk];
                    const float4 h = ((const float4*)cur_s[n])[kk];
                    air[n] += dot4(wr, c); aiz[n] += dot4(wz, c);
                    ahr[n] += dot4(vr, h); ahz[n] += dot4(vz, h);
                }
            }
            const float bir = gru_bih[tid], biz = gru_bih[F_ + tid];
            const float bhr = gru_bhh[tid], bhz = gru_bhh[F_ + tid];
            #pragma unroll
            for (int n = 0; n < NTILE; ++n) {
                r_[n] = sigm(air[n] + bir + ahr[n] + bhr);
                z_[n] = sigm(aiz[n] + biz + ahz[n] + bhz);
            }
        }
        {   // pass 2: n gate + combine + store
            float ain[NTILE], ahn[NTILE];
            #pragma unroll
            for (int n = 0; n < NTILE; ++n) ain[n] = ahn[n] = 0.0f;
            for (int kk = 0; kk < KC; ++kk) {
                const float4 wn = WLOAD(wnT, kk), vn = WLOAD(vnT, kk);
                #pragma unroll
                for (int n = 0; n < NTILE; ++n) {
                    ain[n] += dot4(wn, ((const float4*)ctx_s[n])[kk]);
                    ahn[n] += dot4(vn, ((const float4*)cur_s[n])[kk]);
                }
            }
            const float bin = gru_bih[2*F_ + tid], bhn = gru_bhh[2*F_ + tid];
            #pragma unroll
            for (int n = 0; n < NTILE; ++n) {
                const float nn = tanhf(ain[n] + bin + r_[n] * (ahn[n] + bhn));
                const float h  = (1.0f - z_[n]) * nn + z_[n] * cur_s[n][tid];
                dst[(size_t)(node0 + n) * F_ + tid] = fmaxf(h, 0.0f);
            }
        }
    }
}

// ===================== unified round kernel =====================
// mode 0: nbr feature = lrelu(PA[ni] + PB[bi] + nbr_b); mode 1: = cur_in[ni]
__global__ __launch_bounds__(NT)
void round_kernel(
    const int*   __restrict__ atom_degree,
    const int*   __restrict__ bond_degree,   // unused mode1
    const float* __restrict__ align_W,       // [2F] this round
    const float* __restrict__ align_b,       // [1]
    const float* __restrict__ WT,            // 7 blocked matrices this round
    const float* __restrict__ attend_b,
    const float* __restrict__ gru_bih,
    const float* __restrict__ gru_bhh,
    const float* __restrict__ nbr_b,         // mode0
    const float* __restrict__ PA,            // mode0
    const float* __restrict__ PB,            // mode0
    const float* __restrict__ cur_in,        // [B,L,F]
    float*       __restrict__ dst,
    int mode)
{
    const int node0 = blockIdx.x * NTILE;
    const int bL    = (node0 >> 7) * L_;
    const int tid   = threadIdx.x;

    __shared__ __align__(16) float cur_s  [NTILE][F_];
    __shared__ __align__(16) float mixed_s[NTILE][F_];
    __shared__ __align__(16) float ctx_s  [NTILE][F_];
    __shared__ __align__(16) float alW_s[2 * F_];
    __shared__ __align__(16) float nbrb_s[F_];
    __shared__ float sc_s [NQ];
    __shared__ float asum_s[NTILE];
    __shared__ int   nidx_s[NQ];
    __shared__ int   bidx_s[NQ];

    if (tid < NQ) {
        const int n = tid / D_, j = tid - n * D_;
        nidx_s[tid] = atom_degree[(node0 + n) * D_ + j] & LMASK;
        bidx_s[tid] = (mode == 0) ? (bond_degree[(node0 + n) * D_ + j] & LMASK) : 0;
    }
    for (int i = tid; i < 2 * F_; i += NT) alW_s[i] = align_W[i];
    if (mode == 0) { if (tid < F_) nbrb_s[tid] = nbr_b[tid]; }

    // Phase A: own cur rows
    for (int idx = tid; idx < NTILE * KC; idx += NT) {
        const int n = idx / KC, kk = idx - n * KC;
        ((float4*)cur_s[n])[kk] = ((const float4*)(cur_in + (size_t)(node0 + n) * F_))[kk];
    }
    __syncthreads();

    // Phase C: align scores, 2 lanes per (n,j) pair
    if (tid < NQ * 2) {
        const int q = tid >> 1, sub = tid & 1;
        const int n = q / D_;
        float s = 0.0f;
        for (int k = sub; k < F_; k += 2) s += cur_s[n][k] * alW_s[k];
        if (mode == 0) {
            const float* pa = PA + (size_t)(bL + nidx_s[q]) * F_;
            const float* pb = PB + (size_t)(bL + bidx_s[q]) * F_;
            for (int k = sub; k < F_; k += 2)
                s += lrelu(pa[k] + pb[k] + nbrb_s[k]) * alW_s[F_ + k];
        } else {
            const float* nrow = cur_in + (size_t)(bL + nidx_s[q]) * F_;
            for (int k = sub; k < F_; k += 2) s += nrow[k] * alW_s[F_ + k];
        }
        s += __shfl_xor(s, 1, 2);
        if (sub == 0) {
            float sc = lrelu(s + align_b[0]);
            if (nidx_s[q] == PAD_) sc += -9.0e8f;
            sc_s[q] = sc;
        }
    }
    __syncthreads();

    // masked softmax over D per node
    if (tid < NTILE) {
        float m = sc_s[tid * D_];
        #pragma unroll
        for (int j = 1; j < D_; ++j) m = fmaxf(m, sc_s[tid * D_ + j]);
        float ex[D_]; float ssum = 0.0f;
        #pragma unroll
        for (int j = 0; j < D_; ++j) { ex[j] = __expf(sc_s[tid * D_ + j] - m); ssum += ex[j]; }
        const float inv = 1.0f / ssum;
        float as = 0.0f;
        #pragma unroll
        for (int j = 0; j < D_; ++j) {
            const float a = (nidx_s[tid * D_ + j] == PAD_) ? 0.0f : ex[j] * inv;
            sc_s[tid * D_ + j] = a;
            as += a;
        }
        asum_s[tid] = as;
    }
    __syncthreads();

    // Phase D: mixed[n] = sum_j attn_j * nbr_feat_j (float4 gathers)
    for (int idx = tid; idx < NTILE * KC; idx += NT) {
        const int n = idx / KC, kk = idx - n * KC;
        float4 m4 = make_float4(0.f, 0.f, 0.f, 0.f);
        if (mode == 0) {
            const float4 bb4 = ((const float4*)nbrb_s)[kk];
            #pragma unroll
            for (int j = 0; j < D_; ++j) {
                const float a = sc_s[n * D_ + j];
                const float4 pa4 = ((const float4*)(PA + (size_t)(bL + nidx_s[n*D_+j]) * F_))[kk];
                const float4 pb4 = ((const float4*)(PB + (size_t)(bL + bidx_s[n*D_+j]) * F_))[kk];
                m4.x += a * lrelu(pa4.x + pb4.x + bb4.x);
                m4.y += a * lrelu(pa4.y + pb4.y + bb4.y);
                m4.z += a * lrelu(pa4.z + pb4.z + bb4.z);
                m4.w += a * lrelu(pa4.w + pb4.w + bb4.w);
            }
        } else {
            #pragma unroll
            for (int j = 0; j < D_; ++j) {
                const float a = sc_s[n * D_ + j];
                const float4 v = ((const float4*)(cur_in + (size_t)(bL + nidx_s[n*D_+j]) * F_))[kk];
                m4.x += a * v.x; m4.y += a * v.y; m4.z += a * v.z; m4.w += a * v.w;
            }
        }
        ((float4*)mixed_s[n])[kk] = m4;
    }
    __syncthreads();

    ctx_and_gru(WT, attend_b, gru_bih, gru_bhh,
                cur_s, mixed_s, ctx_s, asum_s, dst, node0, tid);
}

extern "C" __attribute__((visibility("default")))
void kernel_launch(void* const* d_in, const int* in_sizes, int n_in,
                   void* d_out, int out_size, void* d_ws, size_t ws_size,
                   hipStream_t stream) {
    const float* atom_list = (const float*)d_in[0];
    const float* bond_list = (const float*)d_in[1];
    const int*   atom_deg  = (const int*)d_in[2];
    const int*   bond_deg  = (const int*)d_in[3];
    const float* atom_W    = (const float*)d_in[4];
    const float* atom_b    = (const float*)d_in[5];
    const float* nbr_W     = (const float*)d_in[6];
    const float* nbr_b     = (const float*)d_in[7];
    const float* align_W   = (const float*)d_in[8];
    const float* align_b   = (const float*)d_in[9];
    const float* attend_W  = (const float*)d_in[10];
    const float* attend_b  = (const float*)d_in[11];
    const float* gru_Wih   = (const float*)d_in[12];
    const float* gru_Whh   = (const float*)d_in[13];
    const float* gru_bih   = (const float*)d_in[14];
    const float* gru_bhh   = (const float*)d_in[15];

    float* ws   = (float*)d_ws;        // 256 MB available; ~107 MB used
    float* cur0 = ws;                  // [B,L,F] atom embeddings
    float* PA   = ws + (size_t)NF;     // [B,L,F] nbr_W_a @ atom
    float* PB   = ws + (size_t)2*NF;   // [B,L,F] nbr_W_b @ bond
    float* cur1 = ws + (size_t)3*NF;   // [B,L,F] round-0 output
    float* WT   = ws + (size_t)4*NF;   // 14 blocked-transposed F×F matrices
    float* out  = (float*)d_out;

    prep_kernel<<<dim3(B_ * L_ / PN), dim3(NT), 0, stream>>>(
        atom_list, bond_list, atom_W, atom_b, nbr_W, cur0, PA, PB);

    transpose_kernel<<<dim3((14 * MSZ + NT - 1) / NT), dim3(NT), 0, stream>>>(
        attend_W, gru_Wih, gru_Whh, WT);

    const dim3 grid(B_ * L_ / NTILE);
    // round 0
    round_kernel<<<grid, dim3(NT), 0, stream>>>(
        atom_deg, bond_deg, align_W, align_b,
        WT, attend_b, gru_bih, gru_bhh,
        nbr_b, PA, PB, cur0, cur1, 0);
    // round 1
    round_kernel<<<grid, dim3(NT), 0, stream>>>(
        atom_deg, bond_deg, align_W + 2 * F_, align_b + 1,
        WT + (size_t)7 * MSZ, attend_b + F_, gru_bih + 3 * F_, gru_bhh + 3 * F_,
        nbr_b, PA, PB, cur1, out, 1);
}

// Round 14
// 1521.912 us; speedup vs baseline: 2.8506x; 1.0484x over previous
//
#include <hip/hip_runtime.h>

#define B_     256
#define L_     128
#define D_     6
#define F_     200
#define FA_    39
#define FB_    10
#define FAB_   49
#define PAD_   127       // L-1 padding atom index
#define LMASK  127
#define NT     256
#define KC     (F_/4)    // 50 float4 chunks per F-row
#define NTILE  16
#define NQ     (NTILE * D_)   // 96 pairs
#define NF     (B_ * L_ * F_) // 6,553,600 floats
#define MSZ    (F_ * F_)      // 40,000 floats per matrix
#define NNODES (B_ * L_)      // 32768

__device__ __forceinline__ float lrelu(float x) { return x >= 0.0f ? x : 0.01f * x; }
__device__ __forceinline__ float sigm(float x)  { return 1.0f / (1.0f + __expf(-x)); }
__device__ __forceinline__ float dot4(float4 a, float4 b) {
    return a.x*b.x + a.y*b.y + a.z*b.z + a.w*b.w;
}
// coalesced blocked-transposed weight load: lane tid gets W[tid][4kk..4kk+3]
#define WLOAD(base, kk) (((const float4*)((base) + (size_t)(kk) * (F_ * 4)))[tid])

// ============== prep: cur0 = lrelu(atom emb), PA/PB partial nbr emb ==============
#define PN 8
__global__ __launch_bounds__(NT)
void prep_kernel(const float* __restrict__ atom_list, const float* __restrict__ bond_list,
                 const float* __restrict__ atom_W, const float* __restrict__ atom_b,
                 const float* __restrict__ nbr_W,
                 float* __restrict__ cur0, float* __restrict__ PA, float* __restrict__ PB)
{
    const int node0 = blockIdx.x * PN;
    const int tid   = threadIdx.x;
    __shared__ float ga[PN][FA_ + 1];
    __shared__ float gb[PN][FB_ + 2];
    for (int idx = tid; idx < PN * FA_; idx += NT) {
        const int n = idx / FA_, k = idx - n * FA_;
        ga[n][k] = atom_list[(size_t)(node0 + n) * FA_ + k];
    }
    for (int idx = tid; idx < PN * FB_; idx += NT) {
        const int n = idx / FB_, k = idx - n * FB_;
        gb[n][k] = bond_list[(size_t)(node0 + n) * FB_ + k];
    }
    __syncthreads();
    for (int idx = tid; idx < PN * F_; idx += NT) {
        const int n = idx / F_, f = idx - n * F_;
        const float* wa = atom_W + (size_t)f * FA_;
        const float* wn = nbr_W + (size_t)f * FAB_;
        float accA = atom_b[f], accPA = 0.0f, accPB = 0.0f;
        #pragma unroll
        for (int k = 0; k < FA_; ++k) { accA += ga[n][k] * wa[k]; accPA += ga[n][k] * wn[k]; }
        #pragma unroll
        for (int k = 0; k < FB_; ++k) accPB += gb[n][k] * wn[FA_ + k];
        const size_t o = (size_t)(node0 + n) * F_ + f;
        cur0[o] = lrelu(accA);
        PA[o]   = accPA;
        PB[o]   = accPB;
    }
}

// ===== transpose 14 F×F matrices into blocked layout WT4[kk][f][j] =====
__global__ void transpose_kernel(const float* __restrict__ attend_W,
                                 const float* __restrict__ gru_Wih,
                                 const float* __restrict__ gru_Whh,
                                 float* __restrict__ WT)
{
    const int i = blockIdx.x * blockDim.x + threadIdx.x;
    if (i >= 14 * MSZ) return;
    const int m = i / MSZ, rem = i - m * MSZ;
    const int f = rem / F_, k = rem - f * F_;
    const int r = m / 7, t = m - r * 7;
    const float* src;
    if (t == 0)      src = attend_W + (size_t)r * MSZ;
    else if (t <= 3) src = gru_Wih + (size_t)r * 3 * MSZ + (size_t)(t - 1) * MSZ;
    else             src = gru_Whh + (size_t)r * 3 * MSZ + (size_t)(t - 4) * MSZ;
    WT[(size_t)m * MSZ + (size_t)(k >> 2) * (F_ * 4) + f * 4 + (k & 3)] =
        src[(size_t)f * F_ + k];
}

// ===== per-node separable score halves: s1[i]=alW1·feat, s2[i]=alW2·feat =====
#define SN 32   // nodes per block, 8 lanes per node
__global__ __launch_bounds__(NT)
void score_kernel(const float* __restrict__ feat, const float* __restrict__ align_W,
                  float* __restrict__ s1, float* __restrict__ s2)
{
    const int tid  = threadIdx.x;
    const int node = blockIdx.x * SN + (tid >> 3);
    const int sub  = tid & 7;
    const float* row = feat + (size_t)node * F_;
    float a = 0.0f, b = 0.0f;
    for (int k = sub; k < F_; k += 8) {
        const float v = row[k];
        a += v * align_W[k];
        b += v * align_W[F_ + k];
    }
    a += __shfl_xor(a, 1, 8); a += __shfl_xor(a, 2, 8); a += __shfl_xor(a, 4, 8);
    b += __shfl_xor(b, 1, 8); b += __shfl_xor(b, 2, 8); b += __shfl_xor(b, 4, 8);
    if (sub == 0) { s1[node] = a; s2[node] = b; }
}

// ============ shared epilogue: Phase E (ctx) + two-pass GRU ============
__device__ __forceinline__ void ctx_and_gru(
    const float* __restrict__ WT,
    const float* __restrict__ attend_b,
    const float* __restrict__ gru_bih,  const float* __restrict__ gru_bhh,
    float (*cur_s)[F_], float (*mixed_s)[F_], float (*ctx_s)[F_],
    const float* asum_s, float* __restrict__ dst, int node0, int tid)
{
    const float* aT  = WT;
    const float* wrT = WT + 1 * MSZ;
    const float* wzT = WT + 2 * MSZ;
    const float* wnT = WT + 3 * MSZ;
    const float* vrT = WT + 4 * MSZ;
    const float* vzT = WT + 5 * MSZ;
    const float* vnT = WT + 6 * MSZ;

    if (tid < F_) {
        float acc[NTILE];
        #pragma unroll
        for (int n = 0; n < NTILE; ++n) acc[n] = 0.0f;
        for (int kk = 0; kk < KC; ++kk) {
            const float4 w = WLOAD(aT, kk);
            #pragma unroll
            for (int n = 0; n < NTILE; ++n)
                acc[n] += dot4(w, ((const float4*)mixed_s[n])[kk]);
        }
        const float bb = attend_b[tid];
        #pragma unroll
        for (int n = 0; n < NTILE; ++n) {
            const float c = acc[n] + asum_s[n] * bb;
            ctx_s[n][tid] = (c > 0.0f) ? c : (__expf(c) - 1.0f);
        }
    }
    __syncthreads();

    if (tid < F_) {
        float r_[NTILE], z_[NTILE];
        {   // pass 1: r, z gates
            float air[NTILE], aiz[NTILE], ahr[NTILE], ahz[NTILE];
            #pragma unroll
            for (int n = 0; n < NTILE; ++n) air[n] = aiz[n] = ahr[n] = ahz[n] = 0.0f;
            for (int kk = 0; kk < KC; ++kk) {
                const float4 wr = WLOAD(wrT, kk), wz = WLOAD(wzT, kk);
                const float4 vr = WLOAD(vrT, kk), vz = WLOAD(vzT, kk);
                #pragma unroll
                for (int n = 0; n < NTILE; ++n) {
                    const float4 c = ((const float4*)ctx_s[n])[kk];
                    const float4 h = ((const float4*)cur_s[n])[kk];
                    air[n] += dot4(wr, c); aiz[n] += dot4(wz, c);
                    ahr[n] += dot4(vr, h); ahz[n] += dot4(vz, h);
                }
            }
            const float bir = gru_bih[tid], biz = gru_bih[F_ + tid];
            const float bhr = gru_bhh[tid], bhz = gru_bhh[F_ + tid];
            #pragma unroll
            for (int n = 0; n < NTILE; ++n) {
                r_[n] = sigm(air[n] + bir + ahr[n] + bhr);
                z_[n] = sigm(aiz[n] + biz + ahz[n] + bhz);
            }
        }
        {   // pass 2: n gate + combine + store
            float ain[NTILE], ahn[NTILE];
            #pragma unroll
            for (int n = 0; n < NTILE; ++n) ain[n] = ahn[n] = 0.0f;
            for (int kk = 0; kk < KC; ++kk) {
                const float4 wn = WLOAD(wnT, kk), vn = WLOAD(vnT, kk);
                #pragma unroll
                for (int n = 0; n < NTILE; ++n) {
                    ain[n] += dot4(wn, ((const float4*)ctx_s[n])[kk]);
                    ahn[n] += dot4(vn, ((const float4*)cur_s[n])[kk]);
                }
            }
            const float bin = gru_bih[2*F_ + tid], bhn = gru_bhh[2*F_ + tid];
            #pragma unroll
            for (int n = 0; n < NTILE; ++n) {
                const float nn = tanhf(ain[n] + bin + r_[n] * (ahn[n] + bhn));
                const float h  = (1.0f - z_[n]) * nn + z_[n] * cur_s[n][tid];
                dst[(size_t)(node0 + n) * F_ + tid] = fmaxf(h, 0.0f);
            }
        }
    }
}

// ===================== unified round kernel =====================
// mode 0: nbr feature = lrelu(PA[ni]+PB[bi]+nbr_b), pairwise s2 computed here
// mode 1: nbr feature = cur_in[ni], s2 from table
__global__ __launch_bounds__(NT)
void round_kernel(
    const int*   __restrict__ atom_degree,
    const int*   __restrict__ bond_degree,
    const float* __restrict__ align_W,       // [2F] this round (mode0 pairwise half)
    const float* __restrict__ align_b,       // [1]
    const float* __restrict__ WT,
    const float* __restrict__ attend_b,
    const float* __restrict__ gru_bih,
    const float* __restrict__ gru_bhh,
    const float* __restrict__ nbr_b,         // mode0
    const float* __restrict__ PA,            // mode0
    const float* __restrict__ PB,            // mode0
    const float* __restrict__ s1_tab,        // [NNODES] alW1·cur
    const float* __restrict__ s2_tab,        // [NNODES] alW2·cur (mode1)
    const float* __restrict__ cur_in,        // [B,L,F]
    float*       __restrict__ dst,
    int mode)
{
    // XCD swizzle: all 8 tiles of a molecule share (blockIdx % 8) -> same XCD L2
    const int bid   = blockIdx.x;
    const int mol   = ((bid >> 6) << 3) | (bid & 7);
    const int tile  = (bid >> 3) & 7;
    const int node0 = mol * L_ + tile * NTILE;
    const int bL    = mol * L_;
    const int tid   = threadIdx.x;

    __shared__ __align__(16) float cur_s  [NTILE][F_];
    __shared__ __align__(16) float mixed_s[NTILE][F_];
    __shared__ __align__(16) float ctx_s  [NTILE][F_];
    __shared__ __align__(16) float alW2_s[F_];
    __shared__ __align__(16) float nbrb_s[F_];
    __shared__ float sc_s [NQ];
    __shared__ float asum_s[NTILE];
    __shared__ int   nidx_s[NQ];
    __shared__ int   bidx_s[NQ];

    if (tid < NQ) {
        const int n = tid / D_, j = tid - n * D_;
        nidx_s[tid] = atom_degree[(node0 + n) * D_ + j] & LMASK;
        bidx_s[tid] = (mode == 0) ? (bond_degree[(node0 + n) * D_ + j] & LMASK) : 0;
    }
    if (mode == 0 && tid < F_) {
        alW2_s[tid] = align_W[F_ + tid];
        nbrb_s[tid] = nbr_b[tid];
    }

    // Phase A: own cur rows
    for (int idx = tid; idx < NTILE * KC; idx += NT) {
        const int n = idx / KC, kk = idx - n * KC;
        ((float4*)cur_s[n])[kk] = ((const float4*)(cur_in + (size_t)(node0 + n) * F_))[kk];
    }
    __syncthreads();

    // Phase C: align scores
    if (mode == 0) {
        // pairwise neighbor half, 2 lanes per (n,j) pair
        if (tid < NQ * 2) {
            const int q = tid >> 1, sub = tid & 1;
            const int n = q / D_;
            const float* pa = PA + (size_t)(bL + nidx_s[q]) * F_;
            const float* pb = PB + (size_t)(bL + bidx_s[q]) * F_;
            float s = 0.0f;
            for (int k = sub; k < F_; k += 2)
                s += lrelu(pa[k] + pb[k] + nbrb_s[k]) * alW2_s[k];
            s += __shfl_xor(s, 1, 2);
            if (sub == 0) {
                float sc = lrelu(s + s1_tab[node0 + n] + align_b[0]);
                if (nidx_s[q] == PAD_) sc += -9.0e8f;
                sc_s[q] = sc;
            }
        }
    } else {
        if (tid < NQ) {
            const int n = tid / D_;
            float sc = lrelu(s1_tab[node0 + n] + s2_tab[bL + nidx_s[tid]] + align_b[0]);
            if (nidx_s[tid] == PAD_) sc += -9.0e8f;
            sc_s[tid] = sc;
        }
    }
    __syncthreads();

    // masked softmax over D per node
    if (tid < NTILE) {
        float m = sc_s[tid * D_];
        #pragma unroll
        for (int j = 1; j < D_; ++j) m = fmaxf(m, sc_s[tid * D_ + j]);
        float ex[D_]; float ssum = 0.0f;
        #pragma unroll
        for (int j = 0; j < D_; ++j) { ex[j] = __expf(sc_s[tid * D_ + j] - m); ssum += ex[j]; }
        const float inv = 1.0f / ssum;
        float as = 0.0f;
        #pragma unroll
        for (int j = 0; j < D_; ++j) {
            const float a = (nidx_s[tid * D_ + j] == PAD_) ? 0.0f : ex[j] * inv;
            sc_s[tid * D_ + j] = a;
            as += a;
        }
        asum_s[tid] = as;
    }
    __syncthreads();

    // Phase D: mixed[n] = sum_j attn_j * nbr_feat_j (float4 gathers, L2-hot)
    for (int idx = tid; idx < NTILE * KC; idx += NT) {
        const int n = idx / KC, kk = idx - n * KC;
        float4 m4 = make_float4(0.f, 0.f, 0.f, 0.f);
        if (mode == 0) {
            const float4 bb4 = ((const float4*)nbrb_s)[kk];
            #pragma unroll
            for (int j = 0; j < D_; ++j) {
                const float a = sc_s[n * D_ + j];
                const float4 pa4 = ((const float4*)(PA + (size_t)(bL + nidx_s[n*D_+j]) * F_))[kk];
                const float4 pb4 = ((const float4*)(PB + (size_t)(bL + bidx_s[n*D_+j]) * F_))[kk];
                m4.x += a * lrelu(pa4.x + pb4.x + bb4.x);
                m4.y += a * lrelu(pa4.y + pb4.y + bb4.y);
                m4.z += a * lrelu(pa4.z + pb4.z + bb4.z);
                m4.w += a * lrelu(pa4.w + pb4.w + bb4.w);
            }
        } else {
            #pragma unroll
            for (int j = 0; j < D_; ++j) {
                const float a = sc_s[n * D_ + j];
                const float4 v = ((const float4*)(cur_in + (size_t)(bL + nidx_s[n*D_+j]) * F_))[kk];
                m4.x += a * v.x; m4.y += a * v.y; m4.z += a * v.z; m4.w += a * v.w;
            }
        }
        ((float4*)mixed_s[n])[kk] = m4;
    }
    __syncthreads();

    ctx_and_gru(WT, attend_b, gru_bih, gru_bhh,
                cur_s, mixed_s, ctx_s, asum_s, dst, node0, tid);
}

extern "C" __attribute__((visibility("default")))
void kernel_launch(void* const* d_in, const int* in_sizes, int n_in,
                   void* d_out, int out_size, void* d_ws, size_t ws_size,
                   hipStream_t stream) {
    const float* atom_list = (const float*)d_in[0];
    const float* bond_list = (const float*)d_in[1];
    const int*   atom_deg  = (const int*)d_in[2];
    const int*   bond_deg  = (const int*)d_in[3];
    const float* atom_W    = (const float*)d_in[4];
    const float* atom_b    = (const float*)d_in[5];
    const float* nbr_W     = (const float*)d_in[6];
    const float* nbr_b     = (const float*)d_in[7];
    const float* align_W   = (const float*)d_in[8];
    const float* align_b   = (const float*)d_in[9];
    const float* attend_W  = (const float*)d_in[10];
    const float* attend_b  = (const float*)d_in[11];
    const float* gru_Wih   = (const float*)d_in[12];
    const float* gru_Whh   = (const float*)d_in[13];
    const float* gru_bih   = (const float*)d_in[14];
    const float* gru_bhh   = (const float*)d_in[15];

    float* ws   = (float*)d_ws;        // ~108 MB used of 256 MB
    float* cur0 = ws;                  // [B,L,F]
    float* PA   = ws + (size_t)NF;
    float* PB   = ws + (size_t)2*NF;
    float* cur1 = ws + (size_t)3*NF;
    float* WT   = ws + (size_t)4*NF;   // 14 blocked matrices
    float* s1a  = WT + (size_t)14*MSZ; // score tables
    float* s2a  = s1a + NNODES;
    float* s1b  = s2a + NNODES;
    float* s2b  = s1b + NNODES;
    float* out  = (float*)d_out;

    prep_kernel<<<dim3(NNODES / PN), dim3(NT), 0, stream>>>(
        atom_list, bond_list, atom_W, atom_b, nbr_W, cur0, PA, PB);

    transpose_kernel<<<dim3((14 * MSZ + NT - 1) / NT), dim3(NT), 0, stream>>>(
        attend_W, gru_Wih, gru_Whh, WT);

    score_kernel<<<dim3(NNODES / SN), dim3(NT), 0, stream>>>(
        cur0, align_W, s1a, s2a);

    const dim3 grid(NNODES / NTILE);
    round_kernel<<<grid, dim3(NT), 0, stream>>>(
        atom_deg, bond_deg, align_W, align_b,
        WT, attend_b, gru_bih, gru_bhh,
        nbr_b, PA, PB, s1a, s2a, cur0, cur1, 0);

    score_kernel<<<dim3(NNODES / SN), dim3(NT), 0, stream>>>(
        cur1, align_W + 2 * F_, s1b, s2b);

    round_kernel<<<grid, dim3(NT), 0, stream>>>(
        atom_deg, bond_deg, align_W + 2 * F_, align_b + 1,
        WT + (size_t)7 * MSZ, attend_b + F_, gru_bih + 3 * F_, gru_bhh + 3 * F_,
        nbr_b, PA, PB, s1b, s2b, cur1, out, 1);
}

// Round 15
// 1208.808 us; speedup vs baseline: 3.5890x; 1.2590x over previous
//
#include <hip/hip_runtime.h>

#define B_     256
#define L_     128
#define D_     6
#define F_     200
#define FA_    39
#define FB_    10
#define PAD_   127       // L-1 padding atom index
#define LMASK  127
#define NT     256
#define KC     (F_/4)    // 50 float4 chunks per F-row
#define NTILE  16
#define NQ     (NTILE * D_)   // 96 pairs
#define NF     (B_ * L_ * F_) // 6,553,600 floats
#define MSZ    (F_ * F_)      // 40,000 floats per matrix
#define NNODES (B_ * L_)      // 32768
#define KP     224            // K padded to 7*32
#define KSTEPS 7
#define NTL    13             // N tiles of 16 (200 -> 208)
#define FRAG_TOTAL (14 * NTL * KSTEPS * 64)  // frag groups (8 bf16 each)

typedef __attribute__((ext_vector_type(8))) short sh8;
typedef __attribute__((ext_vector_type(4))) float f32x4;

__device__ __forceinline__ float lrelu(float x) { return x >= 0.0f ? x : 0.01f * x; }
__device__ __forceinline__ float sigm(float x)  { return 1.0f / (1.0f + __expf(-x)); }
__device__ __forceinline__ unsigned short f2b(float x) {   // fp32 -> bf16 RNE
    unsigned int u = __float_as_uint(x);
    unsigned int r = (u + 0x7FFFu + ((u >> 16) & 1u)) >> 16;
    return (unsigned short)r;
}
__device__ __forceinline__ uint2 pack4(float4 v) {
    uint2 p;
    p.x = (unsigned int)f2b(v.x) | ((unsigned int)f2b(v.y) << 16);
    p.y = (unsigned int)f2b(v.z) | ((unsigned int)f2b(v.w) << 16);
    return p;
}
// A-fragment read from LDS bf16 [NTILE][KP]: A[m=lane&15][k=ks*32+quad*8+j]
#define AFRAG(arr, ks) (*(const sh8*)&arr[lane & 15][(ks) * 32 + ((lane >> 4) << 3)])
// B-fragment from prebuilt global buffer (per-round base WFr)
__device__ __forceinline__ sh8 bfrag(const unsigned short* __restrict__ WFr,
                                     int mat, int t, int ks, int lane) {
    return *(const sh8*)(WFr + ((((size_t)mat * NTL + t) * KSTEPS + ks) * 64 + lane) * 8);
}

// ============== prep: cur0 = lrelu(atom emb), PA/PB partial nbr emb ==============
#define PN 8
__global__ __launch_bounds__(NT)
void prep_kernel(const float* __restrict__ atom_list, const float* __restrict__ bond_list,
                 const float* __restrict__ atom_W, const float* __restrict__ atom_b,
                 const float* __restrict__ nbr_W,
                 float* __restrict__ cur0, float* __restrict__ PA, float* __restrict__ PB)
{
    const int node0 = blockIdx.x * PN;
    const int tid   = threadIdx.x;
    __shared__ float ga[PN][FA_ + 1];
    __shared__ float gb[PN][FB_ + 2];
    for (int idx = tid; idx < PN * FA_; idx += NT) {
        const int n = idx / FA_, k = idx - n * FA_;
        ga[n][k] = atom_list[(size_t)(node0 + n) * FA_ + k];
    }
    for (int idx = tid; idx < PN * FB_; idx += NT) {
        const int n = idx / FB_, k = idx - n * FB_;
        gb[n][k] = bond_list[(size_t)(node0 + n) * FB_ + k];
    }
    __syncthreads();
    for (int idx = tid; idx < PN * F_; idx += NT) {
        const int n = idx / F_, f = idx - n * F_;
        const float* wa = atom_W + (size_t)f * FA_;
        const float* wn = nbr_W + (size_t)f * (FA_ + FB_);
        float accA = atom_b[f], accPA = 0.0f, accPB = 0.0f;
        #pragma unroll
        for (int k = 0; k < FA_; ++k) { accA += ga[n][k] * wa[k]; accPA += ga[n][k] * wn[k]; }
        #pragma unroll
        for (int k = 0; k < FB_; ++k) accPB += gb[n][k] * wn[FA_ + k];
        const size_t o = (size_t)(node0 + n) * F_ + f;
        cur0[o] = lrelu(accA);
        PA[o]   = accPA;
        PB[o]   = accPB;
    }
}

// ===== build bf16 B-fragments for 14 F×F matrices (zero-padded to 208×224) =====
// m = round*7 + {0:attend, 1..3:Wih r/z/n, 4..6:Whh r/z/n}
__global__ void build_frags(const float* __restrict__ attend_W,
                            const float* __restrict__ gru_Wih,
                            const float* __restrict__ gru_Whh,
                            unsigned short* __restrict__ WF)
{
    const int i = blockIdx.x * blockDim.x + threadIdx.x;
    if (i >= FRAG_TOTAL) return;
    const int lane = i & 63;
    int rest = i >> 6;
    const int ks = rest % KSTEPS; rest /= KSTEPS;
    const int t  = rest % NTL;
    const int m  = rest / NTL;
    const int n  = t * 16 + (lane & 15);
    const int k0 = ks * 32 + ((lane >> 4) << 3);
    const int r = m / 7, tt = m - r * 7;
    const float* src;
    if (tt == 0)      src = attend_W + (size_t)r * MSZ;
    else if (tt <= 3) src = gru_Wih + ((size_t)r * 3 + (tt - 1)) * MSZ;
    else              src = gru_Whh + ((size_t)r * 3 + (tt - 4)) * MSZ;
    unsigned short o[8];
    #pragma unroll
    for (int j = 0; j < 8; ++j) {
        const int k = k0 + j;
        const float v = (n < F_ && k < F_) ? src[(size_t)n * F_ + k] : 0.0f;
        o[j] = f2b(v);
    }
    uint4 w;
    w.x = (unsigned int)o[0] | ((unsigned int)o[1] << 16);
    w.y = (unsigned int)o[2] | ((unsigned int)o[3] << 16);
    w.z = (unsigned int)o[4] | ((unsigned int)o[5] << 16);
    w.w = (unsigned int)o[6] | ((unsigned int)o[7] << 16);
    ((uint4*)WF)[i] = w;
}

// ===== per-node separable score halves =====
#define SN 32
__global__ __launch_bounds__(NT)
void score_kernel(const float* __restrict__ feat, const float* __restrict__ align_W,
                  float* __restrict__ s1, float* __restrict__ s2)
{
    const int tid  = threadIdx.x;
    const int node = blockIdx.x * SN + (tid >> 3);
    const int sub  = tid & 7;
    const float* row = feat + (size_t)node * F_;
    float a = 0.0f, b = 0.0f;
    for (int k = sub; k < F_; k += 8) {
        const float v = row[k];
        a += v * align_W[k];
        b += v * align_W[F_ + k];
    }
    a += __shfl_xor(a, 1, 8); a += __shfl_xor(a, 2, 8); a += __shfl_xor(a, 4, 8);
    b += __shfl_xor(b, 1, 8); b += __shfl_xor(b, 2, 8); b += __shfl_xor(b, 4, 8);
    if (sub == 0) { s1[node] = a; s2[node] = b; }
}

// ===================== round kernel (MFMA E/F) =====================
__global__ __launch_bounds__(NT)
void round_kernel(
    const int*   __restrict__ atom_degree,
    const int*   __restrict__ bond_degree,
    const float* __restrict__ align_W,       // [2F] this round (mode0 pairwise half)
    const float* __restrict__ align_b,       // [1]
    const unsigned short* __restrict__ WF,   // 7 fragment matrices this round
    const float* __restrict__ attend_b,
    const float* __restrict__ gru_bih,
    const float* __restrict__ gru_bhh,
    const float* __restrict__ nbr_b,         // mode0
    const float* __restrict__ PA,            // mode0
    const float* __restrict__ PB,            // mode0
    const float* __restrict__ s1_tab,
    const float* __restrict__ s2_tab,        // mode1
    const float* __restrict__ cur_in,        // [B,L,F]
    float*       __restrict__ dst,
    int mode)
{
    // XCD swizzle: all 8 tiles of a molecule share (blockIdx % 8) -> same XCD L2
    const int bid   = blockIdx.x;
    const int mol   = ((bid >> 6) << 3) | (bid & 7);
    const int tile  = (bid >> 3) & 7;
    const int node0 = mol * L_ + tile * NTILE;
    const int bL    = mol * L_;
    const int tid   = threadIdx.x;
    const int lane  = tid & 63;
    const int wave  = tid >> 6;

    __shared__ __align__(16) float cur_s[NTILE][F_];             // fp32, final combine
    __shared__ __align__(16) unsigned short curb  [NTILE][KP];   // bf16 A-operand
    __shared__ __align__(16) unsigned short mixedb[NTILE][KP];
    __shared__ __align__(16) unsigned short ctxb  [NTILE][KP];
    __shared__ __align__(16) float alW2_s[F_];
    __shared__ __align__(16) float nbrb_s[F_];
    __shared__ float sc_s [NQ];
    __shared__ float asum_s[NTILE];
    __shared__ int   nidx_s[NQ];
    __shared__ int   bidx_s[NQ];

    // zero K-pads (mandatory: A pad x W pad must be 0, LDS is uninitialized)
    for (int idx = tid; idx < NTILE * (KP - F_); idx += NT) {
        const int n = idx / (KP - F_), k = F_ + idx % (KP - F_);
        curb[n][k] = 0; mixedb[n][k] = 0; ctxb[n][k] = 0;
    }

    if (tid < NQ) {
        const int n = tid / D_, j = tid - n * D_;
        nidx_s[tid] = atom_degree[(node0 + n) * D_ + j] & LMASK;
        bidx_s[tid] = (mode == 0) ? (bond_degree[(node0 + n) * D_ + j] & LMASK) : 0;
    }
    if (mode == 0 && tid < F_) {
        alW2_s[tid] = align_W[F_ + tid];
        nbrb_s[tid] = nbr_b[tid];
    }

    // Phase A: own cur rows (fp32 + bf16)
    for (int idx = tid; idx < NTILE * KC; idx += NT) {
        const int n = idx / KC, kk = idx - n * KC;
        const float4 v = ((const float4*)(cur_in + (size_t)(node0 + n) * F_))[kk];
        ((float4*)cur_s[n])[kk] = v;
        *(uint2*)&curb[n][kk * 4] = pack4(v);
    }
    __syncthreads();

    // Phase C: align scores
    if (mode == 0) {
        if (tid < NQ * 2) {
            const int q = tid >> 1, sub = tid & 1;
            const int n = q / D_;
            const float* pa = PA + (size_t)(bL + nidx_s[q]) * F_;
            const float* pb = PB + (size_t)(bL + bidx_s[q]) * F_;
            float s = 0.0f;
            for (int k = sub; k < F_; k += 2)
                s += lrelu(pa[k] + pb[k] + nbrb_s[k]) * alW2_s[k];
            s += __shfl_xor(s, 1, 2);
            if (sub == 0) {
                float sc = lrelu(s + s1_tab[node0 + n] + align_b[0]);
                if (nidx_s[q] == PAD_) sc += -9.0e8f;
                sc_s[q] = sc;
            }
        }
    } else {
        if (tid < NQ) {
            const int n = tid / D_;
            float sc = lrelu(s1_tab[node0 + n] + s2_tab[bL + nidx_s[tid]] + align_b[0]);
            if (nidx_s[tid] == PAD_) sc += -9.0e8f;
            sc_s[tid] = sc;
        }
    }
    __syncthreads();

    // masked softmax over D per node
    if (tid < NTILE) {
        float m = sc_s[tid * D_];
        #pragma unroll
        for (int j = 1; j < D_; ++j) m = fmaxf(m, sc_s[tid * D_ + j]);
        float ex[D_]; float ssum = 0.0f;
        #pragma unroll
        for (int j = 0; j < D_; ++j) { ex[j] = __expf(sc_s[tid * D_ + j] - m); ssum += ex[j]; }
        const float inv = 1.0f / ssum;
        float as = 0.0f;
        #pragma unroll
        for (int j = 0; j < D_; ++j) {
            const float a = (nidx_s[tid * D_ + j] == PAD_) ? 0.0f : ex[j] * inv;
            sc_s[tid * D_ + j] = a;
            as += a;
        }
        asum_s[tid] = as;
    }
    __syncthreads();

    // Phase D: mixed[n] = sum_j attn_j * nbr_feat_j -> bf16 LDS
    for (int idx = tid; idx < NTILE * KC; idx += NT) {
        const int n = idx / KC, kk = idx - n * KC;
        float4 m4 = make_float4(0.f, 0.f, 0.f, 0.f);
        if (mode == 0) {
            const float4 bb4 = ((const float4*)nbrb_s)[kk];
            #pragma unroll
            for (int j = 0; j < D_; ++j) {
                const float a = sc_s[n * D_ + j];
                const float4 pa4 = ((const float4*)(PA + (size_t)(bL + nidx_s[n*D_+j]) * F_))[kk];
                const float4 pb4 = ((const float4*)(PB + (size_t)(bL + bidx_s[n*D_+j]) * F_))[kk];
                m4.x += a * lrelu(pa4.x + pb4.x + bb4.x);
                m4.y += a * lrelu(pa4.y + pb4.y + bb4.y);
                m4.z += a * lrelu(pa4.z + pb4.z + bb4.z);
                m4.w += a * lrelu(pa4.w + pb4.w + bb4.w);
            }
        } else {
            #pragma unroll
            for (int j = 0; j < D_; ++j) {
                const float a = sc_s[n * D_ + j];
                const float4 v = ((const float4*)(cur_in + (size_t)(bL + nidx_s[n*D_+j]) * F_))[kk];
                m4.x += a * v.x; m4.y += a * v.y; m4.z += a * v.z; m4.w += a * v.w;
            }
        }
        *(uint2*)&mixedb[n][kk * 4] = pack4(m4);
    }
    __syncthreads();

    // ---- Phase E (MFMA): ctx = elu(attend_W @ mixed + asum*b) ----
    {
        const f32x4 z4 = {0.f, 0.f, 0.f, 0.f};
        f32x4 acc[4] = {z4, z4, z4, z4};
        for (int ks = 0; ks < KSTEPS; ++ks) {
            const sh8 a = AFRAG(mixedb, ks);
            #pragma unroll
            for (int i = 0; i < 4; ++i) {
                const int t = i * 4 + wave;
                if (t < NTL)
                    acc[i] = __builtin_amdgcn_mfma_f32_16x16x32_bf16(
                        a, bfrag(WF, 0, t, ks, lane), acc[i], 0, 0, 0);
            }
        }
        #pragma unroll
        for (int i = 0; i < 4; ++i) {
            const int t = i * 4 + wave;
            if (t >= NTL) continue;
            const int f = t * 16 + (lane & 15);
            const bool fok = f < F_;
            const float bb = fok ? attend_b[f] : 0.0f;
            #pragma unroll
            for (int rg = 0; rg < 4; ++rg) {
                const int node = ((lane >> 4) << 2) + rg;
                float c = acc[i][rg] + asum_s[node] * bb;
                c = (c > 0.0f) ? c : (__expf(c) - 1.0f);
                if (fok) ctxb[node][f] = f2b(c);
            }
        }
    }
    __syncthreads();

    // ---- Phase F (MFMA): GRU gates ----
    {
        const f32x4 z4 = {0.f, 0.f, 0.f, 0.f};
        f32x4 ar[4]  = {z4, z4, z4, z4};
        f32x4 az[4]  = {z4, z4, z4, z4};
        f32x4 ani[4] = {z4, z4, z4, z4};
        f32x4 anh[4] = {z4, z4, z4, z4};
        for (int ks = 0; ks < KSTEPS; ++ks) {
            const sh8 ac = AFRAG(ctxb, ks);
            const sh8 ah = AFRAG(curb, ks);
            #pragma unroll
            for (int i = 0; i < 4; ++i) {
                const int t = i * 4 + wave;
                if (t >= NTL) continue;
                ar[i]  = __builtin_amdgcn_mfma_f32_16x16x32_bf16(ac, bfrag(WF,1,t,ks,lane), ar[i], 0,0,0);
                ar[i]  = __builtin_amdgcn_mfma_f32_16x16x32_bf16(ah, bfrag(WF,4,t,ks,lane), ar[i], 0,0,0);
                az[i]  = __builtin_amdgcn_mfma_f32_16x16x32_bf16(ac, bfrag(WF,2,t,ks,lane), az[i], 0,0,0);
                az[i]  = __builtin_amdgcn_mfma_f32_16x16x32_bf16(ah, bfrag(WF,5,t,ks,lane), az[i], 0,0,0);
                ani[i] = __builtin_amdgcn_mfma_f32_16x16x32_bf16(ac, bfrag(WF,3,t,ks,lane), ani[i], 0,0,0);
                anh[i] = __builtin_amdgcn_mfma_f32_16x16x32_bf16(ah, bfrag(WF,6,t,ks,lane), anh[i], 0,0,0);
            }
        }
        #pragma unroll
        for (int i = 0; i < 4; ++i) {
            const int t = i * 4 + wave;
            if (t >= NTL) continue;
            const int f = t * 16 + (lane & 15);
            const bool fok = f < F_;
            const float bir = fok ? gru_bih[f]        : 0.f;
            const float biz = fok ? gru_bih[F_ + f]   : 0.f;
            const float bin = fok ? gru_bih[2*F_ + f] : 0.f;
            const float bhr = fok ? gru_bhh[f]        : 0.f;
            const float bhz = fok ? gru_bhh[F_ + f]   : 0.f;
            const float bhn = fok ? gru_bhh[2*F_ + f] : 0.f;
            #pragma unroll
            for (int rg = 0; rg < 4; ++rg) {
                const int node = ((lane >> 4) << 2) + rg;
                const float r  = sigm(ar[i][rg] + bir + bhr);
                const float z  = sigm(az[i][rg] + biz + bhz);
                const float nn = tanhf(ani[i][rg] + bin + r * (anh[i][rg] + bhn));
                if (fok) {
                    const float h = (1.0f - z) * nn + z * cur_s[node][f];
                    dst[(size_t)(node0 + node) * F_ + f] = fmaxf(h, 0.0f);
                }
            }
        }
    }
}

extern "C" __attribute__((visibility("default")))
void kernel_launch(void* const* d_in, const int* in_sizes, int n_in,
                   void* d_out, int out_size, void* d_ws, size_t ws_size,
                   hipStream_t stream) {
    const float* atom_list = (const float*)d_in[0];
    const float* bond_list = (const float*)d_in[1];
    const int*   atom_deg  = (const int*)d_in[2];
    const int*   bond_deg  = (const int*)d_in[3];
    const float* atom_W    = (const float*)d_in[4];
    const float* atom_b    = (const float*)d_in[5];
    const float* nbr_W     = (const float*)d_in[6];
    const float* nbr_b     = (const float*)d_in[7];
    const float* align_W   = (const float*)d_in[8];
    const float* align_b   = (const float*)d_in[9];
    const float* attend_W  = (const float*)d_in[10];
    const float* attend_b  = (const float*)d_in[11];
    const float* gru_Wih   = (const float*)d_in[12];
    const float* gru_Whh   = (const float*)d_in[13];
    const float* gru_bih   = (const float*)d_in[14];
    const float* gru_bhh   = (const float*)d_in[15];

    float* ws   = (float*)d_ws;
    float* cur0 = ws;
    float* PA   = ws + (size_t)NF;
    float* PB   = ws + (size_t)2*NF;
    float* cur1 = ws + (size_t)3*NF;
    float* s1a  = ws + (size_t)4*NF;
    float* s2a  = s1a + NNODES;
    float* s1b  = s2a + NNODES;
    float* s2b  = s1b + NNODES;
    unsigned short* WF = (unsigned short*)(s2b + NNODES);   // 1.3 MB bf16 fragments
    float* out  = (float*)d_out;

    prep_kernel<<<dim3(NNODES / PN), dim3(NT), 0, stream>>>(
        atom_list, bond_list, atom_W, atom_b, nbr_W, cur0, PA, PB);

    build_frags<<<dim3((FRAG_TOTAL + NT - 1) / NT), dim3(NT), 0, stream>>>(
        attend_W, gru_Wih, gru_Whh, WF);

    score_kernel<<<dim3(NNODES / SN), dim3(NT), 0, stream>>>(
        cur0, align_W, s1a, s2a);

    const dim3 grid(NNODES / NTILE);
    const size_t rframe = (size_t)7 * NTL * KSTEPS * 64 * 8;  // shorts per round

    round_kernel<<<grid, dim3(NT), 0, stream>>>(
        atom_deg, bond_deg, align_W, align_b,
        WF, attend_b, gru_bih, gru_bhh,
        nbr_b, PA, PB, s1a, s2a, cur0, cur1, 0);

    score_kernel<<<dim3(NNODES / SN), dim3(NT), 0, stream>>>(
        cur1, align_W + 2 * F_, s1b, s2b);

    round_kernel<<<grid, dim3(NT), 0, stream>>>(
        atom_deg, bond_deg, align_W + 2 * F_, align_b + 1,
        WF + rframe, attend_b + F_, gru_bih + 3 * F_, gru_bhh + 3 * F_,
        nbr_b, PA, PB, s1b, s2b, cur1, out, 1);
}

// Round 16
// 736.444 us; speedup vs baseline: 5.8910x; 1.6414x over previous
//
#include <hip/hip_runtime.h>

#define B_     256
#define L_     128
#define D_     6
#define F_     200
#define FA_    39
#define FB_    10
#define PAD_   127       // L-1 padding atom index
#define LMASK  127
#define NT     256
#define KC     (F_/4)    // 50 float4 chunks per F-row
#define NTILE  16
#define NQ     (NTILE * D_)   // 96 pairs
#define NF     (B_ * L_ * F_) // 6,553,600 floats
#define MSZ    (F_ * F_)      // 40,000 floats per matrix
#define NNODES (B_ * L_)      // 32768
#define KP     224            // K padded to 7*32 (MFMA reads k < 224)
#define KPP    232            // LDS row stride: 464B -> bank step 20 (conflict-free)
#define KSTEPS 7
#define NTL    13             // N tiles of 16 (200 -> 208)
#define FRAG_TOTAL (14 * NTL * KSTEPS * 64)

typedef __attribute__((ext_vector_type(8))) short sh8;
typedef __attribute__((ext_vector_type(4))) float f32x4;

__device__ __forceinline__ float lrelu(float x) { return x >= 0.0f ? x : 0.01f * x; }
__device__ __forceinline__ float sigm(float x)  { return 1.0f / (1.0f + __expf(-x)); }
__device__ __forceinline__ unsigned short f2b(float x) {   // fp32 -> bf16 RNE
    unsigned int u = __float_as_uint(x);
    unsigned int r = (u + 0x7FFFu + ((u >> 16) & 1u)) >> 16;
    return (unsigned short)r;
}
__device__ __forceinline__ uint2 pack4(float4 v) {
    uint2 p;
    p.x = (unsigned int)f2b(v.x) | ((unsigned int)f2b(v.y) << 16);
    p.y = (unsigned int)f2b(v.z) | ((unsigned int)f2b(v.w) << 16);
    return p;
}
// A-fragment from LDS bf16 [NTILE][KPP]: A[m=lane&15][k=ks*32+quad*8+j]
#define AFRAG(arr, ks) (*(const sh8*)&arr[lane & 15][(ks) * 32 + ((lane >> 4) << 3)])
__device__ __forceinline__ sh8 bfrag(const unsigned short* __restrict__ WFr,
                                     int mat, int t, int ks, int lane) {
    return *(const sh8*)(WFr + ((((size_t)mat * NTL + t) * KSTEPS + ks) * 64 + lane) * 8);
}

// ============== prep: cur0 = lrelu(atom emb), PA/PB partial nbr emb ==============
#define PN 8
__global__ __launch_bounds__(NT)
void prep_kernel(const float* __restrict__ atom_list, const float* __restrict__ bond_list,
                 const float* __restrict__ atom_W, const float* __restrict__ atom_b,
                 const float* __restrict__ nbr_W,
                 float* __restrict__ cur0, float* __restrict__ PA, float* __restrict__ PB)
{
    const int node0 = blockIdx.x * PN;
    const int tid   = threadIdx.x;
    __shared__ float ga[PN][FA_ + 1];
    __shared__ float gb[PN][FB_ + 2];
    for (int idx = tid; idx < PN * FA_; idx += NT) {
        const int n = idx / FA_, k = idx - n * FA_;
        ga[n][k] = atom_list[(size_t)(node0 + n) * FA_ + k];
    }
    for (int idx = tid; idx < PN * FB_; idx += NT) {
        const int n = idx / FB_, k = idx - n * FB_;
        gb[n][k] = bond_list[(size_t)(node0 + n) * FB_ + k];
    }
    __syncthreads();
    for (int idx = tid; idx < PN * F_; idx += NT) {
        const int n = idx / F_, f = idx - n * F_;
        const float* wa = atom_W + (size_t)f * FA_;
        const float* wn = nbr_W + (size_t)f * (FA_ + FB_);
        float accA = atom_b[f], accPA = 0.0f, accPB = 0.0f;
        #pragma unroll
        for (int k = 0; k < FA_; ++k) { accA += ga[n][k] * wa[k]; accPA += ga[n][k] * wn[k]; }
        #pragma unroll
        for (int k = 0; k < FB_; ++k) accPB += gb[n][k] * wn[FA_ + k];
        const size_t o = (size_t)(node0 + n) * F_ + f;
        cur0[o] = lrelu(accA);
        PA[o]   = accPA;
        PB[o]   = accPB;
    }
}

// ===== build bf16 B-fragments for 14 F×F matrices (zero-padded to 208×224) =====
__global__ void build_frags(const float* __restrict__ attend_W,
                            const float* __restrict__ gru_Wih,
                            const float* __restrict__ gru_Whh,
                            unsigned short* __restrict__ WF)
{
    const int i = blockIdx.x * blockDim.x + threadIdx.x;
    if (i >= FRAG_TOTAL) return;
    const int lane = i & 63;
    int rest = i >> 6;
    const int ks = rest % KSTEPS; rest /= KSTEPS;
    const int t  = rest % NTL;
    const int m  = rest / NTL;
    const int n  = t * 16 + (lane & 15);
    const int k0 = ks * 32 + ((lane >> 4) << 3);
    const int r = m / 7, tt = m - r * 7;
    const float* src;
    if (tt == 0)      src = attend_W + (size_t)r * MSZ;
    else if (tt <= 3) src = gru_Wih + ((size_t)r * 3 + (tt - 1)) * MSZ;
    else              src = gru_Whh + ((size_t)r * 3 + (tt - 4)) * MSZ;
    unsigned short o[8];
    #pragma unroll
    for (int j = 0; j < 8; ++j) {
        const int k = k0 + j;
        const float v = (n < F_ && k < F_) ? src[(size_t)n * F_ + k] : 0.0f;
        o[j] = f2b(v);
    }
    uint4 w;
    w.x = (unsigned int)o[0] | ((unsigned int)o[1] << 16);
    w.y = (unsigned int)o[2] | ((unsigned int)o[3] << 16);
    w.z = (unsigned int)o[4] | ((unsigned int)o[5] << 16);
    w.w = (unsigned int)o[6] | ((unsigned int)o[7] << 16);
    ((uint4*)WF)[i] = w;
}

// ===== gathered score half only: s2[i] = alW2 · feat[i] =====
#define SN 32
__global__ __launch_bounds__(NT)
void score2_kernel(const float* __restrict__ feat, const float* __restrict__ alW2,
                   float* __restrict__ s2)
{
    const int tid  = threadIdx.x;
    const int node = blockIdx.x * SN + (tid >> 3);
    const int sub  = tid & 7;
    const float* row = feat + (size_t)node * F_;
    float b = 0.0f;
    for (int k = sub; k < F_; k += 8) b += row[k] * alW2[k];
    b += __shfl_xor(b, 1, 8); b += __shfl_xor(b, 2, 8); b += __shfl_xor(b, 4, 8);
    if (sub == 0) s2[node] = b;
}

// ===================== round kernel (MFMA E/F, tile-sequential) =====================
__global__ __launch_bounds__(NT)
void round_kernel(
    const int*   __restrict__ atom_degree,
    const int*   __restrict__ bond_degree,
    const float* __restrict__ align_W,       // [2F] this round
    const float* __restrict__ align_b,       // [1]
    const unsigned short* __restrict__ WF,   // 7 fragment matrices this round
    const float* __restrict__ attend_b,
    const float* __restrict__ gru_bih,
    const float* __restrict__ gru_bhh,
    const float* __restrict__ nbr_b,         // mode0
    const float* __restrict__ PA,            // mode0
    const float* __restrict__ PB,            // mode0
    const float* __restrict__ s2_tab,        // mode1 gathered score half
    const float* __restrict__ cur_in,        // [B,L,F]
    float*       __restrict__ dst,
    int mode)
{
    // XCD swizzle: all 8 tiles of a molecule share (blockIdx % 8) -> same XCD L2
    const int bid   = blockIdx.x;
    const int mol   = ((bid >> 6) << 3) | (bid & 7);
    const int tile  = (bid >> 3) & 7;
    const int node0 = mol * L_ + tile * NTILE;
    const int bL    = mol * L_;
    const int tid   = threadIdx.x;
    const int lane  = tid & 63;
    const int wave  = tid >> 6;

    __shared__ __align__(16) float cur_s[NTILE][F_];             // fp32, final combine
    __shared__ __align__(16) unsigned short curb  [NTILE][KPP];  // bf16 A-operands
    __shared__ __align__(16) unsigned short mixedb[NTILE][KPP];
    __shared__ __align__(16) unsigned short ctxb  [NTILE][KPP];
    __shared__ __align__(16) float alW2_s[F_];
    __shared__ __align__(16) float nbrb_s[F_];
    __shared__ float sc_s [NQ];
    __shared__ float asum_s[NTILE];
    __shared__ float s1_s[NTILE];
    __shared__ int   nidx_s[NQ];
    __shared__ int   bidx_s[NQ];

    // zero K-pads [F_, KP) (MFMA reads them; pad x Wpad = 0 required)
    for (int idx = tid; idx < NTILE * (KP - F_); idx += NT) {
        const int n = idx / (KP - F_), k = F_ + idx % (KP - F_);
        curb[n][k] = 0; mixedb[n][k] = 0; ctxb[n][k] = 0;
    }

    if (tid < NQ) {
        const int n = tid / D_, j = tid - n * D_;
        nidx_s[tid] = atom_degree[(node0 + n) * D_ + j] & LMASK;
        bidx_s[tid] = (mode == 0) ? (bond_degree[(node0 + n) * D_ + j] & LMASK) : 0;
    }
    if (mode == 0 && tid < F_) {
        alW2_s[tid] = align_W[F_ + tid];
        nbrb_s[tid] = nbr_b[tid];
    }

    // Phase A: own cur rows (fp32 + bf16)
    for (int idx = tid; idx < NTILE * KC; idx += NT) {
        const int n = idx / KC, kk = idx - n * KC;
        const float4 v = ((const float4*)(cur_in + (size_t)(node0 + n) * F_))[kk];
        ((float4*)cur_s[n])[kk] = v;
        *(uint2*)&curb[n][kk * 4] = pack4(v);
    }
    __syncthreads();

    // inline s1[n] = alW1 · cur[n] (16 lanes per node)
    {
        const int n = tid >> 4, sub = tid & 15;
        float a = 0.0f;
        for (int f = sub; f < F_; f += 16) a += cur_s[n][f] * align_W[f];
        a += __shfl_xor(a, 1, 16); a += __shfl_xor(a, 2, 16);
        a += __shfl_xor(a, 4, 16); a += __shfl_xor(a, 8, 16);
        if (sub == 0) s1_s[n] = a;
    }
    __syncthreads();

    // Phase C: align scores
    if (mode == 0) {
        if (tid < NQ * 2) {      // 2 lanes per pair, float4
            const int q = tid >> 1, sub = tid & 1;
            const int n = q / D_;
            const float4* pa4 = (const float4*)(PA + (size_t)(bL + nidx_s[q]) * F_);
            const float4* pb4 = (const float4*)(PB + (size_t)(bL + bidx_s[q]) * F_);
            float s = 0.0f;
            for (int kk = sub; kk < KC; kk += 2) {
                const float4 pa = pa4[kk], pb = pb4[kk];
                const float4 w  = ((const float4*)alW2_s)[kk];
                const float4 bb = ((const float4*)nbrb_s)[kk];
                s += lrelu(pa.x + pb.x + bb.x) * w.x + lrelu(pa.y + pb.y + bb.y) * w.y
                   + lrelu(pa.z + pb.z + bb.z) * w.z + lrelu(pa.w + pb.w + bb.w) * w.w;
            }
            s += __shfl_xor(s, 1, 2);
            if (sub == 0) {
                float sc = lrelu(s + s1_s[n] + align_b[0]);
                if (nidx_s[q] == PAD_) sc += -9.0e8f;
                sc_s[q] = sc;
            }
        }
    } else {
        if (tid < NQ) {
            const int n = tid / D_;
            float sc = lrelu(s1_s[n] + s2_tab[bL + nidx_s[tid]] + align_b[0]);
            if (nidx_s[tid] == PAD_) sc += -9.0e8f;
            sc_s[tid] = sc;
        }
    }
    __syncthreads();

    // masked softmax over D per node
    if (tid < NTILE) {
        float m = sc_s[tid * D_];
        #pragma unroll
        for (int j = 1; j < D_; ++j) m = fmaxf(m, sc_s[tid * D_ + j]);
        float ex[D_]; float ssum = 0.0f;
        #pragma unroll
        for (int j = 0; j < D_; ++j) { ex[j] = __expf(sc_s[tid * D_ + j] - m); ssum += ex[j]; }
        const float inv = 1.0f / ssum;
        float as = 0.0f;
        #pragma unroll
        for (int j = 0; j < D_; ++j) {
            const float a = (nidx_s[tid * D_ + j] == PAD_) ? 0.0f : ex[j] * inv;
            sc_s[tid * D_ + j] = a;
            as += a;
        }
        asum_s[tid] = as;
    }
    __syncthreads();

    // Phase D: mixed[n] = sum_j attn_j * nbr_feat_j -> bf16 LDS
    for (int idx = tid; idx < NTILE * KC; idx += NT) {
        const int n = idx / KC, kk = idx - n * KC;
        float4 m4 = make_float4(0.f, 0.f, 0.f, 0.f);
        if (mode == 0) {
            const float4 bb4 = ((const float4*)nbrb_s)[kk];
            #pragma unroll
            for (int j = 0; j < D_; ++j) {
                const float a = sc_s[n * D_ + j];
                const float4 pa4 = ((const float4*)(PA + (size_t)(bL + nidx_s[n*D_+j]) * F_))[kk];
                const float4 pb4 = ((const float4*)(PB + (size_t)(bL + bidx_s[n*D_+j]) * F_))[kk];
                m4.x += a * lrelu(pa4.x + pb4.x + bb4.x);
                m4.y += a * lrelu(pa4.y + pb4.y + bb4.y);
                m4.z += a * lrelu(pa4.z + pb4.z + bb4.z);
                m4.w += a * lrelu(pa4.w + pb4.w + bb4.w);
            }
        } else {
            #pragma unroll
            for (int j = 0; j < D_; ++j) {
                const float a = sc_s[n * D_ + j];
                const float4 v = ((const float4*)(cur_in + (size_t)(bL + nidx_s[n*D_+j]) * F_))[kk];
                m4.x += a * v.x; m4.y += a * v.y; m4.z += a * v.z; m4.w += a * v.w;
            }
        }
        *(uint2*)&mixedb[n][kk * 4] = pack4(m4);
    }
    __syncthreads();

    // ---- Phase E (MFMA, tile-sequential): ctx = elu(attend_W @ mixed + asum*b) ----
    for (int t = wave; t < NTL; t += 4) {
        f32x4 acc = {0.f, 0.f, 0.f, 0.f};
        #pragma unroll
        for (int ks = 0; ks < KSTEPS; ++ks)
            acc = __builtin_amdgcn_mfma_f32_16x16x32_bf16(
                AFRAG(mixedb, ks), bfrag(WF, 0, t, ks, lane), acc, 0, 0, 0);
        const int f = t * 16 + (lane & 15);
        if (f < F_) {
            const float bb = attend_b[f];
            #pragma unroll
            for (int rg = 0; rg < 4; ++rg) {
                const int node = ((lane >> 4) << 2) + rg;
                float c = acc[rg] + asum_s[node] * bb;
                c = (c > 0.0f) ? c : (__expf(c) - 1.0f);
                ctxb[node][f] = f2b(c);
            }
        }
    }
    __syncthreads();

    // ---- Phase F (MFMA, tile-sequential): GRU gates ----
    for (int t = wave; t < NTL; t += 4) {
        f32x4 ar = {0.f,0.f,0.f,0.f}, az = {0.f,0.f,0.f,0.f};
        f32x4 ani = {0.f,0.f,0.f,0.f}, anh = {0.f,0.f,0.f,0.f};
        #pragma unroll
        for (int ks = 0; ks < KSTEPS; ++ks) {
            const sh8 ac = AFRAG(ctxb, ks);
            const sh8 ah = AFRAG(curb, ks);
            ar  = __builtin_amdgcn_mfma_f32_16x16x32_bf16(ac, bfrag(WF,1,t,ks,lane), ar, 0,0,0);
            ar  = __builtin_amdgcn_mfma_f32_16x16x32_bf16(ah, bfrag(WF,4,t,ks,lane), ar, 0,0,0);
            az  = __builtin_amdgcn_mfma_f32_16x16x32_bf16(ac, bfrag(WF,2,t,ks,lane), az, 0,0,0);
            az  = __builtin_amdgcn_mfma_f32_16x16x32_bf16(ah, bfrag(WF,5,t,ks,lane), az, 0,0,0);
            ani = __builtin_amdgcn_mfma_f32_16x16x32_bf16(ac, bfrag(WF,3,t,ks,lane), ani, 0,0,0);
            anh = __builtin_amdgcn_mfma_f32_16x16x32_bf16(ah, bfrag(WF,6,t,ks,lane), anh, 0,0,0);
        }
        const int f = t * 16 + (lane & 15);
        if (f < F_) {
            const float bir = gru_bih[f],        bhr = gru_bhh[f];
            const float biz = gru_bih[F_ + f],   bhz = gru_bhh[F_ + f];
            const float bin = gru_bih[2*F_ + f], bhn = gru_bhh[2*F_ + f];
            #pragma unroll
            for (int rg = 0; rg < 4; ++rg) {
                const int node = ((lane >> 4) << 2) + rg;
                const float r  = sigm(ar[rg] + bir + bhr);
                const float z  = sigm(az[rg] + biz + bhz);
                const float nn = tanhf(ani[rg] + bin + r * (anh[rg] + bhn));
                const float h  = (1.0f - z) * nn + z * cur_s[node][f];
                dst[(size_t)(node0 + node) * F_ + f] = fmaxf(h, 0.0f);
            }
        }
    }
}

extern "C" __attribute__((visibility("default")))
void kernel_launch(void* const* d_in, const int* in_sizes, int n_in,
                   void* d_out, int out_size, void* d_ws, size_t ws_size,
                   hipStream_t stream) {
    const float* atom_list = (const float*)d_in[0];
    const float* bond_list = (const float*)d_in[1];
    const int*   atom_deg  = (const int*)d_in[2];
    const int*   bond_deg  = (const int*)d_in[3];
    const float* atom_W    = (const float*)d_in[4];
    const float* atom_b    = (const float*)d_in[5];
    const float* nbr_W     = (const float*)d_in[6];
    const float* nbr_b     = (const float*)d_in[7];
    const float* align_W   = (const float*)d_in[8];
    const float* align_b   = (const float*)d_in[9];
    const float* attend_W  = (const float*)d_in[10];
    const float* attend_b  = (const float*)d_in[11];
    const float* gru_Wih   = (const float*)d_in[12];
    const float* gru_Whh   = (const float*)d_in[13];
    const float* gru_bih   = (const float*)d_in[14];
    const float* gru_bhh   = (const float*)d_in[15];

    float* ws   = (float*)d_ws;
    float* cur0 = ws;
    float* PA   = ws + (size_t)NF;
    float* PB   = ws + (size_t)2*NF;
    float* cur1 = ws + (size_t)3*NF;
    float* s2b  = ws + (size_t)4*NF;
    unsigned short* WF = (unsigned short*)(s2b + NNODES);   // 1.3 MB bf16 fragments
    float* out  = (float*)d_out;

    prep_kernel<<<dim3(NNODES / PN), dim3(NT), 0, stream>>>(
        atom_list, bond_list, atom_W, atom_b, nbr_W, cur0, PA, PB);

    build_frags<<<dim3((FRAG_TOTAL + NT - 1) / NT), dim3(NT), 0, stream>>>(
        attend_W, gru_Wih, gru_Whh, WF);

    const dim3 grid(NNODES / NTILE);
    const size_t rframe = (size_t)7 * NTL * KSTEPS * 64 * 8;  // shorts per round

    round_kernel<<<grid, dim3(NT), 0, stream>>>(
        atom_deg, bond_deg, align_W, align_b,
        WF, attend_b, gru_bih, gru_bhh,
        nbr_b, PA, PB, /*s2_tab*/nullptr, cur0, cur1, 0);

    score2_kernel<<<dim3(NNODES / SN), dim3(NT), 0, stream>>>(
        cur1, align_W + 2 * F_ + F_, s2b);

    round_kernel<<<grid, dim3(NT), 0, stream>>>(
        atom_deg, bond_deg, align_W + 2 * F_, align_b + 1,
        WF + rframe, attend_b + F_, gru_bih + 3 * F_, gru_bhh + 3 * F_,
        nbr_b, PA, PB, s2b, cur1, out, 1);
}